// Round 1
// baseline (841.958 us; speedup 1.0000x reference)
//
#include <hip/hip_runtime.h>
#include <hip/hip_bf16.h>

typedef short bf16x8 __attribute__((ext_vector_type(8)));
typedef float f32x4 __attribute__((ext_vector_type(4)));
typedef unsigned short ushort_t;

#define NH 16
#define HD 128
#define SEQ 2048
#define HID 2048
#define NQKV 6144
#define BATCH 2

__device__ __forceinline__ ushort_t f2bf(float x) {
    unsigned u = __builtin_bit_cast(unsigned, x);
    u = (u + 0x7fffu + ((u >> 16) & 1u)) >> 16;
    return (ushort_t)u;
}
__device__ __forceinline__ float bf2f(ushort_t h) {
    unsigned u = ((unsigned)h) << 16;
    return __builtin_bit_cast(float, u);
}

// ---------------------------------------------------------------------------
// Transpose + fp32->bf16: w [K][N] -> wT [N][K] bf16
// ---------------------------------------------------------------------------
__global__ __launch_bounds__(256) void transpose_to_bf16(
    const float* __restrict__ w, ushort_t* __restrict__ wT, int K, int N) {
    __shared__ float tile[32][33];
    int nb = blockIdx.x * 32, kb = blockIdx.y * 32;
    int tx = threadIdx.x, ty = threadIdx.y;  // 32 x 8
#pragma unroll
    for (int i = 0; i < 4; ++i) {
        int k = kb + ty + i * 8;
        tile[ty + i * 8][tx] = w[(size_t)k * N + nb + tx];
    }
    __syncthreads();
#pragma unroll
    for (int i = 0; i < 4; ++i) {
        int n = nb + ty + i * 8;
        wT[(size_t)n * K + kb + tx] = f2bf(tile[tx][ty + i * 8]);
    }
}

// ---------------------------------------------------------------------------
// GEMM 1: qkv = hidden(fp32) @ w_qkv + b_qkv, scatter to q/k/v [B,nh,S,hd] bf16
// 128x128 tile, BK=32, 256 threads (4 waves, each 64x64)
// LDS layout: chunked [kc][m][8] so each mfma frag is one ds_read_b128.
// ---------------------------------------------------------------------------
__global__ __launch_bounds__(256) void gemm_qkv(
    const float* __restrict__ A,          // [4096][2048] fp32
    const ushort_t* __restrict__ BT,      // [6144][2048] bf16 (w_qkv^T)
    const float* __restrict__ bias,       // [6144]
    ushort_t* __restrict__ qbuf, ushort_t* __restrict__ kbuf,
    ushort_t* __restrict__ vbuf) {
    __shared__ uint4 At[512];  // [kc(4)][m(128)]
    __shared__ uint4 Bt[512];  // [kc(4)][n(128)]
    const int mb = blockIdx.x * 128;
    const int nb = blockIdx.y * 128;
    const int t = threadIdx.x;
    const int w = t >> 6, lane = t & 63, lm = lane & 15, lq = lane >> 4;
    const int wm = (w >> 1) * 64, wn = (w & 1) * 64;
    const int am = t >> 1, ahalf = t & 1;

    f32x4 acc[4][4] = {};

    for (int kb = 0; kb < HID; kb += 32) {
        __syncthreads();
        // stage A: 16 fp32 -> 2 bf16x8 chunks
        {
            const float* ap = A + (size_t)(mb + am) * HID + kb + ahalf * 16;
            float4 a0 = *(const float4*)(ap + 0);
            float4 a1 = *(const float4*)(ap + 4);
            float4 a2 = *(const float4*)(ap + 8);
            float4 a3 = *(const float4*)(ap + 12);
            union { ushort_t u[8]; uint4 v; } p0, p1;
            p0.u[0]=f2bf(a0.x); p0.u[1]=f2bf(a0.y); p0.u[2]=f2bf(a0.z); p0.u[3]=f2bf(a0.w);
            p0.u[4]=f2bf(a1.x); p0.u[5]=f2bf(a1.y); p0.u[6]=f2bf(a1.z); p0.u[7]=f2bf(a1.w);
            p1.u[0]=f2bf(a2.x); p1.u[1]=f2bf(a2.y); p1.u[2]=f2bf(a2.z); p1.u[3]=f2bf(a2.w);
            p1.u[4]=f2bf(a3.x); p1.u[5]=f2bf(a3.y); p1.u[6]=f2bf(a3.z); p1.u[7]=f2bf(a3.w);
            At[(ahalf * 2 + 0) * 128 + am] = p0.v;
            At[(ahalf * 2 + 1) * 128 + am] = p1.v;
        }
        // stage B from bf16 transposed weights (contiguous in K)
        {
            const uint4* bp = (const uint4*)(BT + (size_t)(nb + am) * HID) + (kb >> 3) + ahalf * 2;
            Bt[(ahalf * 2 + 0) * 128 + am] = bp[0];
            Bt[(ahalf * 2 + 1) * 128 + am] = bp[1];
        }
        __syncthreads();
        bf16x8 af[4], bfr[4];
#pragma unroll
        for (int mt = 0; mt < 4; ++mt)
            af[mt] = ((const bf16x8*)At)[lq * 128 + wm + mt * 16 + lm];
#pragma unroll
        for (int nt = 0; nt < 4; ++nt)
            bfr[nt] = ((const bf16x8*)Bt)[lq * 128 + wn + nt * 16 + lm];
#pragma unroll
        for (int mt = 0; mt < 4; ++mt)
#pragma unroll
            for (int nt = 0; nt < 4; ++nt)
                acc[mt][nt] = __builtin_amdgcn_mfma_f32_16x16x32_bf16(
                    af[mt], bfr[nt], acc[mt][nt], 0, 0, 0);
    }

    // epilogue: +bias, scatter to q/k/v [B][nh][S][hd] bf16
#pragma unroll
    for (int mt = 0; mt < 4; ++mt)
#pragma unroll
        for (int nt = 0; nt < 4; ++nt)
#pragma unroll
            for (int r = 0; r < 4; ++r) {
                int m = mb + wm + mt * 16 + lq * 4 + r;
                int c = nb + wn + nt * 16 + lm;
                float val = acc[mt][nt][r] + bias[c];
                int sec = c >> 11;
                int h = (c >> 7) & 15;
                int d = c & 127;
                int b = m >> 11, s = m & 2047;
                ushort_t* dst = (sec == 0) ? qbuf : (sec == 1) ? kbuf : vbuf;
                dst[(((size_t)(b * NH + h)) * SEQ + s) * HD + d] = f2bf(val);
            }
}

// ---------------------------------------------------------------------------
// Flash attention with ALiBi + causal. One block = (b,h,64 q rows), 4 waves
// each own 16 q rows. K/V tiles of 32 keys staged in LDS.
// ---------------------------------------------------------------------------
__global__ __launch_bounds__(256) void attn_kernel(
    const ushort_t* __restrict__ qb, const ushort_t* __restrict__ kbuf,
    const ushort_t* __restrict__ vbuf, ushort_t* __restrict__ ob) {
    __shared__ ushort_t Qs[64 * 136];   // padded rows: 2-way banks only
    __shared__ ushort_t Ks[32 * 136];
    __shared__ uint4 Vs[512];           // chunked [kc(4)][d(128)] of 8 keys
    __shared__ ushort_t Ps[4][16 * 40]; // per-wave P scratch, rows padded to 40

    const int bid = blockIdx.x;
    const int qt = bid & 31;
    const int h = (bid >> 5) & 15;
    const int b = bid >> 9;
    const int bh = b * NH + h;
    const int qbase = qt * 64;
    const int t = threadIdx.x, w = t >> 6, lane = t & 63;
    const int lm = lane & 15, lq = lane >> 4;

    const ushort_t* Qg = qb + (size_t)bh * SEQ * HD;
    const ushort_t* Kg = kbuf + (size_t)bh * SEQ * HD;
    const ushort_t* Vg = vbuf + (size_t)bh * SEQ * HD;

    // stage Q tile [64][128]
    for (int idx = t; idx < 64 * 16; idx += 256) {
        int r = idx >> 4, c = idx & 15;
        *(uint4*)&Qs[r * 136 + c * 8] =
            *(const uint4*)(Qg + (size_t)(qbase + r) * HD + c * 8);
    }

    const float slope = exp2f(-0.5f * (float)(h + 1));
    const float scale = 1.0f / 128.0f;
    float m_r[4], l_r[4];
#pragma unroll
    for (int r = 0; r < 4; ++r) { m_r[r] = -1e30f; l_r[r] = 0.0f; }
    f32x4 O[8] = {};

    const int nkt = (qbase + 64) / 32;
    for (int kt = 0; kt < nkt; ++kt) {
        __syncthreads();
        // stage K tile [32][128] and V tile (transposed-chunked)
        for (int idx = t; idx < 512; idx += 256) {
            int r = idx >> 4, c = idx & 15;  // key row, d-chunk
            *(uint4*)&Ks[r * 136 + c * 8] =
                *(const uint4*)(Kg + (size_t)(kt * 32 + r) * HD + c * 8);
            uint4 vv = *(const uint4*)(Vg + (size_t)(kt * 32 + r) * HD + c * 8);
            const ushort_t* pv = (const ushort_t*)&vv;
            int kc = r >> 3, kj = r & 7;
            ushort_t* vsu = (ushort_t*)Vs;
#pragma unroll
            for (int j = 0; j < 8; ++j)
                vsu[((kc * 128 + (c * 8 + j)) << 3) + kj] = pv[j];
        }
        __syncthreads();

        // S = Q K^T  (16 q x 32 k per wave)
        f32x4 sacc[2] = {};
#pragma unroll
        for (int kc = 0; kc < 4; ++kc) {
            bf16x8 aq = *(const bf16x8*)&Qs[(w * 16 + lm) * 136 + kc * 32 + lq * 8];
#pragma unroll
            for (int nt = 0; nt < 2; ++nt) {
                bf16x8 bk = *(const bf16x8*)&Ks[(nt * 16 + lm) * 136 + kc * 32 + lq * 8];
                sacc[nt] = __builtin_amdgcn_mfma_f32_16x16x32_bf16(aq, bk, sacc[nt], 0, 0, 0);
            }
        }

        // scale + alibi + causal mask (C layout: row=lq*4+r, col=lm)
        float sc[2][4];
#pragma unroll
        for (int nt = 0; nt < 2; ++nt)
#pragma unroll
            for (int r = 0; r < 4; ++r) {
                int qg = qbase + w * 16 + lq * 4 + r;
                int kg = kt * 32 + nt * 16 + lm;
                float s = sacc[nt][r] * scale + slope * (float)(kg - qg);
                sc[nt][r] = (kg <= qg) ? s : -1e30f;
            }

        // online softmax update
        float alpha[4];
#pragma unroll
        for (int r = 0; r < 4; ++r) {
            float tm = fmaxf(sc[0][r], sc[1][r]);
#pragma unroll
            for (int msk = 8; msk >= 1; msk >>= 1) tm = fmaxf(tm, __shfl_xor(tm, msk));
            float mnew = fmaxf(m_r[r], tm);
            alpha[r] = __expf(m_r[r] - mnew);
            m_r[r] = mnew;
        }
#pragma unroll
        for (int r = 0; r < 4; ++r) {
            float psum = 0.0f;
#pragma unroll
            for (int nt = 0; nt < 2; ++nt) {
                float p = __expf(sc[nt][r] - m_r[r]);
                ushort_t pb = f2bf(p);
                Ps[w][(lq * 4 + r) * 40 + nt * 16 + lm] = pb;
                psum += bf2f(pb);
            }
#pragma unroll
            for (int msk = 8; msk >= 1; msk >>= 1) psum += __shfl_xor(psum, msk);
            l_r[r] = l_r[r] * alpha[r] + psum;
        }
        // rescale O
#pragma unroll
        for (int nt2 = 0; nt2 < 8; ++nt2)
#pragma unroll
            for (int r = 0; r < 4; ++r) O[nt2][r] *= alpha[r];

        // P (C layout) -> A layout via per-wave LDS round trip
        asm volatile("s_waitcnt lgkmcnt(0)" ::: "memory");
        bf16x8 ap = *(const bf16x8*)&Ps[w][lm * 40 + lq * 8];
#pragma unroll
        for (int nt2 = 0; nt2 < 8; ++nt2) {
            bf16x8 bv = *(const bf16x8*)&((ushort_t*)Vs)[(lq * 128 + nt2 * 16 + lm) * 8];
            O[nt2] = __builtin_amdgcn_mfma_f32_16x16x32_bf16(ap, bv, O[nt2], 0, 0, 0);
        }
    }

    // epilogue: O / l -> [B][S][H] bf16
#pragma unroll
    for (int nt2 = 0; nt2 < 8; ++nt2)
#pragma unroll
        for (int r = 0; r < 4; ++r) {
            int s = qbase + w * 16 + lq * 4 + r;
            int d = nt2 * 16 + lm;
            float val = O[nt2][r] / l_r[r];
            ob[((size_t)(b * SEQ + s)) * HID + h * HD + d] = f2bf(val);
        }
}

// ---------------------------------------------------------------------------
// GEMM 2: out = attn(bf16) @ w_proj + b_proj -> fp32
// ---------------------------------------------------------------------------
__global__ __launch_bounds__(256) void gemm_proj(
    const ushort_t* __restrict__ A,    // [4096][2048] bf16
    const ushort_t* __restrict__ BT,   // [2048][2048] bf16 (w_proj^T)
    const float* __restrict__ bias,    // [2048]
    float* __restrict__ out) {
    __shared__ uint4 At[512];
    __shared__ uint4 Bt[512];
    const int mb = blockIdx.x * 128;
    const int nb = blockIdx.y * 128;
    const int t = threadIdx.x;
    const int w = t >> 6, lane = t & 63, lm = lane & 15, lq = lane >> 4;
    const int wm = (w >> 1) * 64, wn = (w & 1) * 64;
    const int am = t >> 1, ahalf = t & 1;

    f32x4 acc[4][4] = {};

    for (int kb = 0; kb < HID; kb += 32) {
        __syncthreads();
        {
            const uint4* ap = (const uint4*)(A + (size_t)(mb + am) * HID) + (kb >> 3) + ahalf * 2;
            At[(ahalf * 2 + 0) * 128 + am] = ap[0];
            At[(ahalf * 2 + 1) * 128 + am] = ap[1];
        }
        {
            const uint4* bp = (const uint4*)(BT + (size_t)(nb + am) * HID) + (kb >> 3) + ahalf * 2;
            Bt[(ahalf * 2 + 0) * 128 + am] = bp[0];
            Bt[(ahalf * 2 + 1) * 128 + am] = bp[1];
        }
        __syncthreads();
        bf16x8 af[4], bfr[4];
#pragma unroll
        for (int mt = 0; mt < 4; ++mt)
            af[mt] = ((const bf16x8*)At)[lq * 128 + wm + mt * 16 + lm];
#pragma unroll
        for (int nt = 0; nt < 4; ++nt)
            bfr[nt] = ((const bf16x8*)Bt)[lq * 128 + wn + nt * 16 + lm];
#pragma unroll
        for (int mt = 0; mt < 4; ++mt)
#pragma unroll
            for (int nt = 0; nt < 4; ++nt)
                acc[mt][nt] = __builtin_amdgcn_mfma_f32_16x16x32_bf16(
                    af[mt], bfr[nt], acc[mt][nt], 0, 0, 0);
    }

#pragma unroll
    for (int mt = 0; mt < 4; ++mt)
#pragma unroll
        for (int nt = 0; nt < 4; ++nt)
#pragma unroll
            for (int r = 0; r < 4; ++r) {
                int m = mb + wm + mt * 16 + lq * 4 + r;
                int c = nb + wn + nt * 16 + lm;
                out[(size_t)m * HID + c] = acc[mt][nt][r] + bias[c];
            }
}

// ---------------------------------------------------------------------------
extern "C" void kernel_launch(void* const* d_in, const int* in_sizes, int n_in,
                              void* d_out, int out_size, void* d_ws, size_t ws_size,
                              hipStream_t stream) {
    const float* hidden = (const float*)d_in[0];
    const float* w_qkv = (const float*)d_in[1];
    const float* b_qkv = (const float*)d_in[2];
    const float* w_proj = (const float*)d_in[3];
    const float* b_proj = (const float*)d_in[4];
    float* out = (float*)d_out;

    char* ws = (char*)d_ws;
    size_t off = 0;
    ushort_t* wqkvT = (ushort_t*)(ws + off); off += (size_t)NQKV * HID * 2;   // 25.2 MB
    ushort_t* wprojT = (ushort_t*)(ws + off); off += (size_t)HID * HID * 2;   // 8.4 MB
    ushort_t* qw = (ushort_t*)(ws + off); off += (size_t)BATCH * NH * SEQ * HD * 2;
    ushort_t* kw = (ushort_t*)(ws + off); off += (size_t)BATCH * NH * SEQ * HD * 2;
    ushort_t* vw = (ushort_t*)(ws + off); off += (size_t)BATCH * NH * SEQ * HD * 2;
    ushort_t* attnw = (ushort_t*)(ws + off); off += (size_t)BATCH * SEQ * HID * 2;

    // 1. transpose-convert weights
    transpose_to_bf16<<<dim3(NQKV / 32, HID / 32), dim3(32, 8), 0, stream>>>(
        w_qkv, wqkvT, HID, NQKV);
    transpose_to_bf16<<<dim3(HID / 32, HID / 32), dim3(32, 8), 0, stream>>>(
        w_proj, wprojT, HID, HID);

    // 2. qkv projection
    gemm_qkv<<<dim3(BATCH * SEQ / 128, NQKV / 128), 256, 0, stream>>>(
        hidden, wqkvT, b_qkv, qw, kw, vw);

    // 3. attention
    attn_kernel<<<dim3(BATCH * NH * (SEQ / 64)), 256, 0, stream>>>(qw, kw, vw, attnw);

    // 4. output projection
    gemm_proj<<<dim3(BATCH * SEQ / 128, HID / 128), 256, 0, stream>>>(
        attnw, wprojT, b_proj, out);
}

// Round 2
// 521.259 us; speedup vs baseline: 1.6152x; 1.6152x over previous
//
#include <hip/hip_runtime.h>
#include <hip/hip_bf16.h>

typedef short bf16x8 __attribute__((ext_vector_type(8)));
typedef float f32x4 __attribute__((ext_vector_type(4)));
typedef unsigned short ushort_t;

#define NH 16
#define HD 128
#define SEQ 2048
#define HID 2048
#define NQKV 6144
#define BATCH 2

__device__ __forceinline__ ushort_t f2bf(float x) {
    unsigned u = __builtin_bit_cast(unsigned, x);
    u = (u + 0x7fffu + ((u >> 16) & 1u)) >> 16;
    return (ushort_t)u;
}
__device__ __forceinline__ float bf2f(ushort_t h) {
    unsigned u = ((unsigned)h) << 16;
    return __builtin_bit_cast(float, u);
}

// ---------------------------------------------------------------------------
// fp32 -> bf16 elementwise (hidden states), 8 elems/thread
// ---------------------------------------------------------------------------
__global__ __launch_bounds__(256) void to_bf16(
    const float* __restrict__ x, ushort_t* __restrict__ y, int n8) {
    int i = blockIdx.x * 256 + threadIdx.x;
    if (i >= n8) return;
    float4 a0 = *(const float4*)(x + (size_t)i * 8);
    float4 a1 = *(const float4*)(x + (size_t)i * 8 + 4);
    union { ushort_t u[8]; uint4 v; } p;
    p.u[0]=f2bf(a0.x); p.u[1]=f2bf(a0.y); p.u[2]=f2bf(a0.z); p.u[3]=f2bf(a0.w);
    p.u[4]=f2bf(a1.x); p.u[5]=f2bf(a1.y); p.u[6]=f2bf(a1.z); p.u[7]=f2bf(a1.w);
    *(uint4*)(y + (size_t)i * 8) = p.v;
}

// ---------------------------------------------------------------------------
// Transpose + fp32->bf16: w [K][N] -> wT [N][K] bf16
// ---------------------------------------------------------------------------
__global__ __launch_bounds__(256) void transpose_to_bf16(
    const float* __restrict__ w, ushort_t* __restrict__ wT, int K, int N) {
    __shared__ float tile[32][33];
    int nb = blockIdx.x * 32, kb = blockIdx.y * 32;
    int tx = threadIdx.x, ty = threadIdx.y;  // 32 x 8
#pragma unroll
    for (int i = 0; i < 4; ++i) {
        int k = kb + ty + i * 8;
        tile[ty + i * 8][tx] = w[(size_t)k * N + nb + tx];
    }
    __syncthreads();
#pragma unroll
    for (int i = 0; i < 4; ++i) {
        int n = nb + ty + i * 8;
        wT[(size_t)n * K + kb + tx] = f2bf(tile[tx][ty + i * 8]);
    }
}

// ---------------------------------------------------------------------------
// GEMM 1: qkv = hidden(bf16) @ w_qkv + b_qkv
// q,k -> [B,nh,S,hd] bf16 ; v -> TRANSPOSED [B,nh,hd,S] bf16
// 128x128 tile, BK=32, 256 threads (4 waves, each 64x64)
// ---------------------------------------------------------------------------
__global__ __launch_bounds__(256) void gemm_qkv(
    const ushort_t* __restrict__ A,       // [4096][2048] bf16 hidden
    const ushort_t* __restrict__ BT,      // [6144][2048] bf16 (w_qkv^T)
    const float* __restrict__ bias,       // [6144]
    ushort_t* __restrict__ qbuf, ushort_t* __restrict__ kbuf,
    ushort_t* __restrict__ vTbuf) {
    __shared__ uint4 At[512];  // [kc(4)][m(128)]
    __shared__ uint4 Bt[512];  // [kc(4)][n(128)]
    const int mb = blockIdx.x * 128;
    const int nb = blockIdx.y * 128;
    const int t = threadIdx.x;
    const int w = t >> 6, lane = t & 63, lm = lane & 15, lq = lane >> 4;
    const int wm = (w >> 1) * 64, wn = (w & 1) * 64;
    const int am = t >> 1, ahalf = t & 1;

    f32x4 acc[4][4] = {};

    for (int kb = 0; kb < HID; kb += 32) {
        __syncthreads();
        {
            const uint4* ap = (const uint4*)(A + (size_t)(mb + am) * HID) + (kb >> 3) + ahalf * 2;
            At[(ahalf * 2 + 0) * 128 + am] = ap[0];
            At[(ahalf * 2 + 1) * 128 + am] = ap[1];
        }
        {
            const uint4* bp = (const uint4*)(BT + (size_t)(nb + am) * HID) + (kb >> 3) + ahalf * 2;
            Bt[(ahalf * 2 + 0) * 128 + am] = bp[0];
            Bt[(ahalf * 2 + 1) * 128 + am] = bp[1];
        }
        __syncthreads();
        bf16x8 af[4], bfr[4];
#pragma unroll
        for (int mt = 0; mt < 4; ++mt)
            af[mt] = ((const bf16x8*)At)[lq * 128 + wm + mt * 16 + lm];
#pragma unroll
        for (int nt = 0; nt < 4; ++nt)
            bfr[nt] = ((const bf16x8*)Bt)[lq * 128 + wn + nt * 16 + lm];
#pragma unroll
        for (int mt = 0; mt < 4; ++mt)
#pragma unroll
            for (int nt = 0; nt < 4; ++nt)
                acc[mt][nt] = __builtin_amdgcn_mfma_f32_16x16x32_bf16(
                    af[mt], bfr[nt], acc[mt][nt], 0, 0, 0);
    }

#pragma unroll
    for (int mt = 0; mt < 4; ++mt)
#pragma unroll
        for (int nt = 0; nt < 4; ++nt)
#pragma unroll
            for (int r = 0; r < 4; ++r) {
                int m = mb + wm + mt * 16 + lq * 4 + r;
                int c = nb + wn + nt * 16 + lm;
                float val = acc[mt][nt][r] + bias[c];
                int sec = c >> 11;
                int h = (c >> 7) & 15;
                int d = c & 127;
                int b = m >> 11, s = m & 2047;
                size_t bh = (size_t)(b * NH + h);
                if (sec == 0)
                    qbuf[(bh * SEQ + s) * HD + d] = f2bf(val);
                else if (sec == 1)
                    kbuf[(bh * SEQ + s) * HD + d] = f2bf(val);
                else
                    vTbuf[(bh * HD + d) * SEQ + s] = f2bf(val);
            }
}

// ---------------------------------------------------------------------------
// Flash attention with ALiBi + causal. One block = (b,h, q-tile pair i,31-i)
// so every block does exactly 66 key-tile iterations (load-balanced).
// 4 waves, each owns 16 q rows of the 64-row tile. 32-key K/V tiles in LDS.
// V arrives pre-transposed [B,h,d,S] -> conflict-free b128 staging.
// ---------------------------------------------------------------------------
__global__ __launch_bounds__(256) void attn_kernel(
    const ushort_t* __restrict__ qb, const ushort_t* __restrict__ kbuf,
    const ushort_t* __restrict__ vT, ushort_t* __restrict__ ob) {
    __shared__ ushort_t Qs[64 * 136];   // q rows, pad 136 -> 2-way banks
    __shared__ ushort_t Ks[32 * 136];   // key rows
    __shared__ ushort_t Vs[128 * 36];   // [d][k] pad 36 -> 2-way banks
    __shared__ ushort_t Ps[4][16 * 40]; // per-wave P scratch

    const int bid = blockIdx.x;
    const int pair = bid & 15;
    const int h = (bid >> 4) & 15;
    const int b = bid >> 8;
    const int bh = b * NH + h;
    const int t = threadIdx.x, w = t >> 6, lane = t & 63;
    const int lm = lane & 15, lq = lane >> 4;

    const ushort_t* Qg = qb + (size_t)bh * SEQ * HD;
    const ushort_t* Kg = kbuf + (size_t)bh * SEQ * HD;
    const ushort_t* Vg = vT + (size_t)bh * HD * SEQ;

    const float slope = exp2f(-0.5f * (float)(h + 1));
    const float scale = 1.0f / 128.0f;

    for (int half = 0; half < 2; ++half) {
        const int qt = half ? (31 - pair) : pair;
        const int qbase = qt * 64;

        __syncthreads();  // all waves done with previous half's LDS
        // stage Q tile [64][128]
        for (int idx = t; idx < 64 * 16; idx += 256) {
            int r = idx >> 4, c = idx & 15;
            *(uint4*)&Qs[r * 136 + c * 8] =
                *(const uint4*)(Qg + (size_t)(qbase + r) * HD + c * 8);
        }

        float m_r[4], l_r[4];
#pragma unroll
        for (int r = 0; r < 4; ++r) { m_r[r] = -1e30f; l_r[r] = 0.0f; }
        f32x4 O[8] = {};

        const int nkt = (qbase + 64) / 32;
        for (int kt = 0; kt < nkt; ++kt) {
            __syncthreads();
            // stage K tile [32 keys][128 d]
            for (int idx = t; idx < 512; idx += 256) {
                int r = idx >> 4, c = idx & 15;
                *(uint4*)&Ks[r * 136 + c * 8] =
                    *(const uint4*)(Kg + (size_t)(kt * 32 + r) * HD + c * 8);
            }
            // stage V^T tile [128 d][32 k] - vectorized, no scatter
            for (int idx = t; idx < 512; idx += 256) {
                int d = idx >> 2, c = idx & 3;
                *(uint4*)&Vs[d * 36 + c * 8] =
                    *(const uint4*)(Vg + (size_t)d * SEQ + kt * 32 + c * 8);
            }
            __syncthreads();

            // S = Q K^T  (16 q x 32 k per wave)
            f32x4 sacc[2] = {};
#pragma unroll
            for (int kc = 0; kc < 4; ++kc) {
                bf16x8 aq = *(const bf16x8*)&Qs[(w * 16 + lm) * 136 + kc * 32 + lq * 8];
#pragma unroll
                for (int nt = 0; nt < 2; ++nt) {
                    bf16x8 bk = *(const bf16x8*)&Ks[(nt * 16 + lm) * 136 + kc * 32 + lq * 8];
                    sacc[nt] = __builtin_amdgcn_mfma_f32_16x16x32_bf16(aq, bk, sacc[nt], 0, 0, 0);
                }
            }

            // scale + alibi + causal mask (C layout: row=lq*4+r, col=lm)
            float sc[2][4];
#pragma unroll
            for (int nt = 0; nt < 2; ++nt)
#pragma unroll
                for (int r = 0; r < 4; ++r) {
                    int qg = qbase + w * 16 + lq * 4 + r;
                    int kg = kt * 32 + nt * 16 + lm;
                    float s = sacc[nt][r] * scale + slope * (float)(kg - qg);
                    sc[nt][r] = (kg <= qg) ? s : -1e30f;
                }

            // online softmax update
            float alpha[4];
#pragma unroll
            for (int r = 0; r < 4; ++r) {
                float tm = fmaxf(sc[0][r], sc[1][r]);
#pragma unroll
                for (int msk = 8; msk >= 1; msk >>= 1) tm = fmaxf(tm, __shfl_xor(tm, msk));
                float mnew = fmaxf(m_r[r], tm);
                alpha[r] = __expf(m_r[r] - mnew);
                m_r[r] = mnew;
            }
#pragma unroll
            for (int r = 0; r < 4; ++r) {
                float psum = 0.0f;
#pragma unroll
                for (int nt = 0; nt < 2; ++nt) {
                    float p = __expf(sc[nt][r] - m_r[r]);
                    ushort_t pb = f2bf(p);
                    Ps[w][(lq * 4 + r) * 40 + nt * 16 + lm] = pb;
                    psum += bf2f(pb);
                }
#pragma unroll
                for (int msk = 8; msk >= 1; msk >>= 1) psum += __shfl_xor(psum, msk);
                l_r[r] = l_r[r] * alpha[r] + psum;
            }
            // rescale O
#pragma unroll
            for (int nt2 = 0; nt2 < 8; ++nt2)
#pragma unroll
                for (int r = 0; r < 4; ++r) O[nt2][r] *= alpha[r];

            // P (C layout) -> A layout via per-wave LDS round trip
            asm volatile("s_waitcnt lgkmcnt(0)" ::: "memory");
            bf16x8 ap = *(const bf16x8*)&Ps[w][lm * 40 + lq * 8];
#pragma unroll
            for (int nt2 = 0; nt2 < 8; ++nt2) {
                bf16x8 bv = *(const bf16x8*)&Vs[(nt2 * 16 + lm) * 36 + lq * 8];
                O[nt2] = __builtin_amdgcn_mfma_f32_16x16x32_bf16(ap, bv, O[nt2], 0, 0, 0);
            }
        }

        // epilogue: O / l -> [B][S][H] bf16
#pragma unroll
        for (int nt2 = 0; nt2 < 8; ++nt2)
#pragma unroll
            for (int r = 0; r < 4; ++r) {
                int s = qbase + w * 16 + lq * 4 + r;
                int d = nt2 * 16 + lm;
                float val = O[nt2][r] / l_r[r];
                ob[((size_t)(b * SEQ + s)) * HID + h * HD + d] = f2bf(val);
            }
    }
}

// ---------------------------------------------------------------------------
// GEMM 2: out = attn(bf16) @ w_proj + b_proj -> fp32
// ---------------------------------------------------------------------------
__global__ __launch_bounds__(256) void gemm_proj(
    const ushort_t* __restrict__ A,    // [4096][2048] bf16
    const ushort_t* __restrict__ BT,   // [2048][2048] bf16 (w_proj^T)
    const float* __restrict__ bias,    // [2048]
    float* __restrict__ out) {
    __shared__ uint4 At[512];
    __shared__ uint4 Bt[512];
    const int mb = blockIdx.x * 128;
    const int nb = blockIdx.y * 128;
    const int t = threadIdx.x;
    const int w = t >> 6, lane = t & 63, lm = lane & 15, lq = lane >> 4;
    const int wm = (w >> 1) * 64, wn = (w & 1) * 64;
    const int am = t >> 1, ahalf = t & 1;

    f32x4 acc[4][4] = {};

    for (int kb = 0; kb < HID; kb += 32) {
        __syncthreads();
        {
            const uint4* ap = (const uint4*)(A + (size_t)(mb + am) * HID) + (kb >> 3) + ahalf * 2;
            At[(ahalf * 2 + 0) * 128 + am] = ap[0];
            At[(ahalf * 2 + 1) * 128 + am] = ap[1];
        }
        {
            const uint4* bp = (const uint4*)(BT + (size_t)(nb + am) * HID) + (kb >> 3) + ahalf * 2;
            Bt[(ahalf * 2 + 0) * 128 + am] = bp[0];
            Bt[(ahalf * 2 + 1) * 128 + am] = bp[1];
        }
        __syncthreads();
        bf16x8 af[4], bfr[4];
#pragma unroll
        for (int mt = 0; mt < 4; ++mt)
            af[mt] = ((const bf16x8*)At)[lq * 128 + wm + mt * 16 + lm];
#pragma unroll
        for (int nt = 0; nt < 4; ++nt)
            bfr[nt] = ((const bf16x8*)Bt)[lq * 128 + wn + nt * 16 + lm];
#pragma unroll
        for (int mt = 0; mt < 4; ++mt)
#pragma unroll
            for (int nt = 0; nt < 4; ++nt)
                acc[mt][nt] = __builtin_amdgcn_mfma_f32_16x16x32_bf16(
                    af[mt], bfr[nt], acc[mt][nt], 0, 0, 0);
    }

#pragma unroll
    for (int mt = 0; mt < 4; ++mt)
#pragma unroll
        for (int nt = 0; nt < 4; ++nt)
#pragma unroll
            for (int r = 0; r < 4; ++r) {
                int m = mb + wm + mt * 16 + lq * 4 + r;
                int c = nb + wn + nt * 16 + lm;
                out[(size_t)m * HID + c] = acc[mt][nt][r] + bias[c];
            }
}

// ---------------------------------------------------------------------------
extern "C" void kernel_launch(void* const* d_in, const int* in_sizes, int n_in,
                              void* d_out, int out_size, void* d_ws, size_t ws_size,
                              hipStream_t stream) {
    const float* hidden = (const float*)d_in[0];
    const float* w_qkv = (const float*)d_in[1];
    const float* b_qkv = (const float*)d_in[2];
    const float* w_proj = (const float*)d_in[3];
    const float* b_proj = (const float*)d_in[4];
    float* out = (float*)d_out;

    char* ws = (char*)d_ws;
    size_t off = 0;
    ushort_t* wqkvT = (ushort_t*)(ws + off); off += (size_t)NQKV * HID * 2;
    ushort_t* wprojT = (ushort_t*)(ws + off); off += (size_t)HID * HID * 2;
    ushort_t* hbf = (ushort_t*)(ws + off); off += (size_t)BATCH * SEQ * HID * 2;
    ushort_t* qw = (ushort_t*)(ws + off); off += (size_t)BATCH * NH * SEQ * HD * 2;
    ushort_t* kw = (ushort_t*)(ws + off); off += (size_t)BATCH * NH * SEQ * HD * 2;
    ushort_t* vTw = (ushort_t*)(ws + off); off += (size_t)BATCH * NH * SEQ * HD * 2;
    ushort_t* attnw = (ushort_t*)(ws + off); off += (size_t)BATCH * SEQ * HID * 2;

    // 1. convert inputs to bf16 (weights transposed)
    to_bf16<<<dim3(BATCH * SEQ * HID / 8 / 256), 256, 0, stream>>>(
        hidden, hbf, BATCH * SEQ * HID / 8);
    transpose_to_bf16<<<dim3(NQKV / 32, HID / 32), dim3(32, 8), 0, stream>>>(
        w_qkv, wqkvT, HID, NQKV);
    transpose_to_bf16<<<dim3(HID / 32, HID / 32), dim3(32, 8), 0, stream>>>(
        w_proj, wprojT, HID, HID);

    // 2. qkv projection (v written transposed)
    gemm_qkv<<<dim3(BATCH * SEQ / 128, NQKV / 128), 256, 0, stream>>>(
        hbf, wqkvT, b_qkv, qw, kw, vTw);

    // 3. attention (load-balanced q-tile pairs)
    attn_kernel<<<dim3(BATCH * NH * 16), 256, 0, stream>>>(qw, kw, vTw, attnw);

    // 4. output projection
    gemm_proj<<<dim3(BATCH * SEQ / 128, HID / 128), 256, 0, stream>>>(
        attnw, wprojT, b_proj, out);
}

// Round 3
// 472.638 us; speedup vs baseline: 1.7814x; 1.1029x over previous
//
#include <hip/hip_runtime.h>
#include <hip/hip_bf16.h>

typedef short bf16x8 __attribute__((ext_vector_type(8)));
typedef float f32x4 __attribute__((ext_vector_type(4)));
typedef unsigned short ushort_t;

#define NH 16
#define HD 128
#define SEQ 2048
#define HID 2048
#define NQKV 6144
#define BATCH 2

__device__ __forceinline__ ushort_t f2bf(float x) {
    unsigned u = __builtin_bit_cast(unsigned, x);
    u = (u + 0x7fffu + ((u >> 16) & 1u)) >> 16;
    return (ushort_t)u;
}

// async global->LDS, 16B per lane. LDS dest = uniform base + lane*16.
__device__ __forceinline__ void gl2lds16(const ushort_t* g, ushort_t* l) {
    __builtin_amdgcn_global_load_lds(
        (__attribute__((address_space(1))) void*)(g),
        (__attribute__((address_space(3))) void*)(l), 16, 0, 0);
}

// ---------------------------------------------------------------------------
// fp32 -> bf16 elementwise (hidden states), 8 elems/thread
// ---------------------------------------------------------------------------
__global__ __launch_bounds__(256) void to_bf16(
    const float* __restrict__ x, ushort_t* __restrict__ y, int n8) {
    int i = blockIdx.x * 256 + threadIdx.x;
    if (i >= n8) return;
    float4 a0 = *(const float4*)(x + (size_t)i * 8);
    float4 a1 = *(const float4*)(x + (size_t)i * 8 + 4);
    union { ushort_t u[8]; uint4 v; } p;
    p.u[0]=f2bf(a0.x); p.u[1]=f2bf(a0.y); p.u[2]=f2bf(a0.z); p.u[3]=f2bf(a0.w);
    p.u[4]=f2bf(a1.x); p.u[5]=f2bf(a1.y); p.u[6]=f2bf(a1.z); p.u[7]=f2bf(a1.w);
    *(uint4*)(y + (size_t)i * 8) = p.v;
}

// ---------------------------------------------------------------------------
// Transpose + fp32->bf16: w [K][N] -> wT [N][K] bf16
// ---------------------------------------------------------------------------
__global__ __launch_bounds__(256) void transpose_to_bf16(
    const float* __restrict__ w, ushort_t* __restrict__ wT, int K, int N) {
    __shared__ float tile[32][33];
    int nb = blockIdx.x * 32, kb = blockIdx.y * 32;
    int tx = threadIdx.x, ty = threadIdx.y;  // 32 x 8
#pragma unroll
    for (int i = 0; i < 4; ++i) {
        int k = kb + ty + i * 8;
        tile[ty + i * 8][tx] = w[(size_t)k * N + nb + tx];
    }
    __syncthreads();
#pragma unroll
    for (int i = 0; i < 4; ++i) {
        int n = nb + ty + i * 8;
        wT[(size_t)n * K + kb + tx] = f2bf(tile[tx][ty + i * 8]);
    }
}

// ---------------------------------------------------------------------------
// m97-style GEMM core: 128x128 tile, BK=64, global_load_lds(16B) staging with
// XOR-swizzled chunk order. LDS[r][slot s] holds global k-chunk s^(r&7).
// ---------------------------------------------------------------------------
#define GEMM_KLOOP(A_, BT_)                                                     \
    const int t = threadIdx.x;                                                  \
    const int w = t >> 6, lane = t & 63, lm = lane & 15, lq = lane >> 4;        \
    const int wm = (w >> 1) * 64, wn = (w & 1) * 64;                            \
    const int lrow = lane >> 3, lsw = (lane & 7) ^ lrow;                        \
    f32x4 acc[4][4] = {};                                                       \
    const ushort_t* gA = A_ + (size_t)(mb + w * 32 + lrow) * HID + lsw * 8;     \
    const ushort_t* gB = BT_ + (size_t)(nb + w * 32 + lrow) * HID + lsw * 8;    \
    for (int kb = 0; kb < HID; kb += 64) {                                      \
        __syncthreads();                                                        \
        _Pragma("unroll")                                                       \
        for (int c = 0; c < 4; ++c) {                                           \
            gl2lds16(gA + (size_t)c * 8 * HID + kb, At + (w * 256 + c * 64) * 8); \
            gl2lds16(gB + (size_t)c * 8 * HID + kb, Bt + (w * 256 + c * 64) * 8); \
        }                                                                       \
        __syncthreads();                                                        \
        _Pragma("unroll")                                                       \
        for (int kc = 0; kc < 2; ++kc) {                                        \
            const int slot = (kc * 4 + lq) ^ (lm & 7);                          \
            bf16x8 af[4], bfr[4];                                               \
            _Pragma("unroll")                                                   \
            for (int mt = 0; mt < 4; ++mt)                                      \
                af[mt] = ((const bf16x8*)At)[(wm + mt * 16 + lm) * 8 + slot];   \
            _Pragma("unroll")                                                   \
            for (int nt = 0; nt < 4; ++nt)                                      \
                bfr[nt] = ((const bf16x8*)Bt)[(wn + nt * 16 + lm) * 8 + slot];  \
            _Pragma("unroll")                                                   \
            for (int mt = 0; mt < 4; ++mt)                                      \
                _Pragma("unroll")                                               \
                for (int nt = 0; nt < 4; ++nt)                                  \
                    acc[mt][nt] = __builtin_amdgcn_mfma_f32_16x16x32_bf16(      \
                        af[mt], bfr[nt], acc[mt][nt], 0, 0, 0);                 \
        }                                                                       \
    }

// GEMM 1: qkv = hidden(bf16) @ w_qkv + b_qkv; q,k -> [B,nh,S,hd]; v -> [B,nh,hd,S]
__global__ __launch_bounds__(256) void gemm_qkv(
    const ushort_t* __restrict__ A, const ushort_t* __restrict__ BT,
    const float* __restrict__ bias,
    ushort_t* __restrict__ qbuf, ushort_t* __restrict__ kbuf,
    ushort_t* __restrict__ vTbuf) {
    __shared__ ushort_t At[128 * 64];
    __shared__ ushort_t Bt[128 * 64];
    const int mb = blockIdx.x * 128;
    const int nb = blockIdx.y * 128;
    GEMM_KLOOP(A, BT)
#pragma unroll
    for (int mt = 0; mt < 4; ++mt)
#pragma unroll
        for (int nt = 0; nt < 4; ++nt)
#pragma unroll
            for (int r = 0; r < 4; ++r) {
                int m = mb + wm + mt * 16 + lq * 4 + r;
                int c = nb + wn + nt * 16 + lm;
                float val = acc[mt][nt][r] + bias[c];
                int sec = c >> 11;
                int h = (c >> 7) & 15;
                int d = c & 127;
                int b = m >> 11, s = m & 2047;
                size_t bh = (size_t)(b * NH + h);
                if (sec == 0)
                    qbuf[(bh * SEQ + s) * HD + d] = f2bf(val);
                else if (sec == 1)
                    kbuf[(bh * SEQ + s) * HD + d] = f2bf(val);
                else
                    vTbuf[(bh * HD + d) * SEQ + s] = f2bf(val);
            }
}

// GEMM 2: out = attn(bf16) @ w_proj + b_proj -> fp32
__global__ __launch_bounds__(256) void gemm_proj(
    const ushort_t* __restrict__ A, const ushort_t* __restrict__ BT,
    const float* __restrict__ bias, float* __restrict__ out) {
    __shared__ ushort_t At[128 * 64];
    __shared__ ushort_t Bt[128 * 64];
    const int mb = blockIdx.x * 128;
    const int nb = blockIdx.y * 128;
    GEMM_KLOOP(A, BT)
#pragma unroll
    for (int mt = 0; mt < 4; ++mt)
#pragma unroll
        for (int nt = 0; nt < 4; ++nt)
#pragma unroll
            for (int r = 0; r < 4; ++r) {
                int m = mb + wm + mt * 16 + lq * 4 + r;
                int c = nb + wn + nt * 16 + lm;
                out[(size_t)m * HID + c] = acc[mt][nt][r] + bias[c];
            }
}

// ---------------------------------------------------------------------------
// Flash attention, S^T formulation: S^T = K Q^T so each lane's scores all
// belong to one q row (q = lane&15) -> scalar softmax state, 2-shuffle
// reductions. Log2-domain softmax. Balanced q-tile pairs (i, 31-i).
// ---------------------------------------------------------------------------
__global__ __launch_bounds__(256) void attn_kernel(
    const ushort_t* __restrict__ qb, const ushort_t* __restrict__ kbuf,
    const ushort_t* __restrict__ vT, ushort_t* __restrict__ ob) {
    __shared__ ushort_t Qs[64 * 136];
    __shared__ ushort_t Ks[32 * 136];
    __shared__ ushort_t Vs[128 * 36];
    __shared__ ushort_t Ps[4][16 * 40];

    const int bid = blockIdx.x;
    const int pair = bid & 15;
    const int h = (bid >> 4) & 15;
    const int b = bid >> 8;
    const int bh = b * NH + h;
    const int t = threadIdx.x, w = t >> 6, lane = t & 63;
    const int lm = lane & 15, lq = lane >> 4;

    const ushort_t* Qg = qb + (size_t)bh * SEQ * HD;
    const ushort_t* Kg = kbuf + (size_t)bh * SEQ * HD;
    const ushort_t* Vg = vT + (size_t)bh * HD * SEQ;

    const float LOG2E = 1.44269504f;
    const float slope2 = exp2f(-0.5f * (float)(h + 1)) * LOG2E;
    const float scale2 = (1.0f / 128.0f) * LOG2E;

    // per-lane score offsets (keys within tile), hoisted
    float foff[2][4];
    int koff[2][4];
#pragma unroll
    for (int mt = 0; mt < 2; ++mt)
#pragma unroll
        for (int r = 0; r < 4; ++r) {
            koff[mt][r] = mt * 16 + lq * 4 + r;
            foff[mt][r] = slope2 * (float)koff[mt][r];
        }

    // K/V staging indices (2 x uint4 each per thread)
    const int kr0 = t >> 4, kc0 = t & 15;          // K rows 0..15 / 16..31
    const int vd0 = t >> 2, vc0 = t & 3;           // V d 0..63 / 64..127

    for (int half = 0; half < 2; ++half) {
        const int qt = half ? (31 - pair) : pair;
        const int qbase = qt * 64;
        const int qg = qbase + w * 16 + lm;  // this lane's q row

        __syncthreads();  // prev half's compute fully done
        for (int idx = t; idx < 64 * 16; idx += 256) {
            int r = idx >> 4, c = idx & 15;
            *(uint4*)&Qs[r * 136 + c * 8] =
                *(const uint4*)(Qg + (size_t)(qbase + r) * HD + c * 8);
        }
        __syncthreads();  // Q visible
        bf16x8 qf[4];
#pragma unroll
        for (int kc = 0; kc < 4; ++kc)
            qf[kc] = *(const bf16x8*)&Qs[(w * 16 + lm) * 136 + kc * 32 + lq * 8];

        float mrow = -1e30f, lrow = 0.0f;
        f32x4 O[8] = {};
        const int nkt = (qbase + 64) / 32;

        // preload tile 0 into regs
        uint4 kreg[2], vreg[2];
#pragma unroll
        for (int i = 0; i < 2; ++i) {
            kreg[i] = *(const uint4*)(Kg + (size_t)(i * 16 + kr0) * HD + kc0 * 8);
            vreg[i] = *(const uint4*)(Vg + (size_t)(i * 64 + vd0) * SEQ + vc0 * 8);
        }

        for (int kt = 0; kt < nkt; ++kt) {
            // store this tile's K/V into LDS
#pragma unroll
            for (int i = 0; i < 2; ++i) {
                *(uint4*)&Ks[(i * 16 + kr0) * 136 + kc0 * 8] = kreg[i];
                *(uint4*)&Vs[(i * 64 + vd0) * 36 + vc0 * 8] = vreg[i];
            }
            // prefetch next tile
            if (kt + 1 < nkt) {
#pragma unroll
                for (int i = 0; i < 2; ++i) {
                    kreg[i] = *(const uint4*)(Kg + (size_t)((kt + 1) * 32 + i * 16 + kr0) * HD + kc0 * 8);
                    vreg[i] = *(const uint4*)(Vg + (size_t)(i * 64 + vd0) * SEQ + (kt + 1) * 32 + vc0 * 8);
                }
            }
            __syncthreads();  // K/V visible

            // S^T = K Q^T : A=K-frag (m=key), B=Q-frag (n=q)
            f32x4 sacc[2] = {};
#pragma unroll
            for (int kc = 0; kc < 4; ++kc) {
#pragma unroll
                for (int mt = 0; mt < 2; ++mt) {
                    bf16x8 bk = *(const bf16x8*)&Ks[(mt * 16 + lm) * 136 + kc * 32 + lq * 8];
                    sacc[mt] = __builtin_amdgcn_mfma_f32_16x16x32_bf16(bk, qf[kc], sacc[mt], 0, 0, 0);
                }
            }

            // scores (log2 domain), per lane all for q = qg
            const float sbase = slope2 * (float)(kt * 32 - qg);
            float sc[2][4];
            if (kt >= nkt - 2) {
#pragma unroll
                for (int mt = 0; mt < 2; ++mt)
#pragma unroll
                    for (int r = 0; r < 4; ++r) {
                        float s = sacc[mt][r] * scale2 + (sbase + foff[mt][r]);
                        sc[mt][r] = (kt * 32 + koff[mt][r] <= qg) ? s : -3e38f;
                    }
            } else {
#pragma unroll
                for (int mt = 0; mt < 2; ++mt)
#pragma unroll
                    for (int r = 0; r < 4; ++r)
                        sc[mt][r] = sacc[mt][r] * scale2 + (sbase + foff[mt][r]);
            }

            // max: 7 in-lane + 2 shuffles (reduce over lq)
            float tm = sc[0][0];
#pragma unroll
            for (int mt = 0; mt < 2; ++mt)
#pragma unroll
                for (int r = 0; r < 4; ++r) tm = fmaxf(tm, sc[mt][r]);
            tm = fmaxf(tm, __shfl_xor(tm, 16));
            tm = fmaxf(tm, __shfl_xor(tm, 32));
            float mnew = fmaxf(mrow, tm);
            float alpha = __builtin_amdgcn_exp2f(mrow - mnew);
            mrow = mnew;

            // p = exp2(sc - m), pack to Ps[q][key], sum
            float psum = 0.0f;
#pragma unroll
            for (int mt = 0; mt < 2; ++mt) {
                float p0 = __builtin_amdgcn_exp2f(sc[mt][0] - mnew);
                float p1 = __builtin_amdgcn_exp2f(sc[mt][1] - mnew);
                float p2 = __builtin_amdgcn_exp2f(sc[mt][2] - mnew);
                float p3 = __builtin_amdgcn_exp2f(sc[mt][3] - mnew);
                psum += (p0 + p1) + (p2 + p3);
                uint2 wv;
                wv.x = ((unsigned)f2bf(p1) << 16) | f2bf(p0);
                wv.y = ((unsigned)f2bf(p3) << 16) | f2bf(p2);
                *(uint2*)&Ps[w][lm * 40 + mt * 16 + lq * 4] = wv;
            }
            psum += __shfl_xor(psum, 16);
            psum += __shfl_xor(psum, 32);
            lrow = lrow * alpha + psum;

            // broadcast alpha to O rows (O row q = lq*4+r lives at lane lq*4+r)
            float av[4];
#pragma unroll
            for (int r = 0; r < 4; ++r) av[r] = __shfl(alpha, lq * 4 + r);
#pragma unroll
            for (int nt = 0; nt < 8; ++nt)
#pragma unroll
                for (int r = 0; r < 4; ++r) O[nt][r] *= av[r];

            // PV: A = P (q=lane&15, k=keys), B = V^T
            asm volatile("s_waitcnt lgkmcnt(0)" ::: "memory");
            bf16x8 ap = *(const bf16x8*)&Ps[w][lm * 40 + lq * 8];
#pragma unroll
            for (int nt = 0; nt < 8; ++nt) {
                bf16x8 bv = *(const bf16x8*)&Vs[(nt * 16 + lm) * 36 + lq * 8];
                O[nt] = __builtin_amdgcn_mfma_f32_16x16x32_bf16(ap, bv, O[nt], 0, 0, 0);
            }
            __syncthreads();  // compute done before next tile's LDS store
        }

        // epilogue: broadcast l, divide, store
        float lb[4];
#pragma unroll
        for (int r = 0; r < 4; ++r)
            lb[r] = __builtin_amdgcn_rcpf(__shfl(lrow, lq * 4 + r));
#pragma unroll
        for (int nt = 0; nt < 8; ++nt)
#pragma unroll
            for (int r = 0; r < 4; ++r) {
                int s = qbase + w * 16 + lq * 4 + r;
                int d = nt * 16 + lm;
                ob[((size_t)(b * SEQ + s)) * HID + h * HD + d] = f2bf(O[nt][r] * lb[r]);
            }
    }
}

// ---------------------------------------------------------------------------
extern "C" void kernel_launch(void* const* d_in, const int* in_sizes, int n_in,
                              void* d_out, int out_size, void* d_ws, size_t ws_size,
                              hipStream_t stream) {
    const float* hidden = (const float*)d_in[0];
    const float* w_qkv = (const float*)d_in[1];
    const float* b_qkv = (const float*)d_in[2];
    const float* w_proj = (const float*)d_in[3];
    const float* b_proj = (const float*)d_in[4];
    float* out = (float*)d_out;

    char* ws = (char*)d_ws;
    size_t off = 0;
    ushort_t* wqkvT = (ushort_t*)(ws + off); off += (size_t)NQKV * HID * 2;
    ushort_t* wprojT = (ushort_t*)(ws + off); off += (size_t)HID * HID * 2;
    ushort_t* hbf = (ushort_t*)(ws + off); off += (size_t)BATCH * SEQ * HID * 2;
    ushort_t* qw = (ushort_t*)(ws + off); off += (size_t)BATCH * NH * SEQ * HD * 2;
    ushort_t* kw = (ushort_t*)(ws + off); off += (size_t)BATCH * NH * SEQ * HD * 2;
    ushort_t* vTw = (ushort_t*)(ws + off); off += (size_t)BATCH * NH * SEQ * HD * 2;
    ushort_t* attnw = (ushort_t*)(ws + off); off += (size_t)BATCH * SEQ * HID * 2;

    to_bf16<<<dim3(BATCH * SEQ * HID / 8 / 256), 256, 0, stream>>>(
        hidden, hbf, BATCH * SEQ * HID / 8);
    transpose_to_bf16<<<dim3(NQKV / 32, HID / 32), dim3(32, 8), 0, stream>>>(
        w_qkv, wqkvT, HID, NQKV);
    transpose_to_bf16<<<dim3(HID / 32, HID / 32), dim3(32, 8), 0, stream>>>(
        w_proj, wprojT, HID, HID);

    gemm_qkv<<<dim3(BATCH * SEQ / 128, NQKV / 128), 256, 0, stream>>>(
        hbf, wqkvT, b_qkv, qw, kw, vTw);

    attn_kernel<<<dim3(BATCH * NH * 16), 256, 0, stream>>>(qw, kw, vTw, attnw);

    gemm_proj<<<dim3(BATCH * SEQ / 128, HID / 128), 256, 0, stream>>>(
        attnw, wprojT, b_proj, out);
}

// Round 4
// 378.156 us; speedup vs baseline: 2.2265x; 1.2498x over previous
//
#include <hip/hip_runtime.h>
#include <hip/hip_bf16.h>

typedef short bf16x8 __attribute__((ext_vector_type(8)));
typedef float f32x4 __attribute__((ext_vector_type(4)));
typedef unsigned short ushort_t;

#define NH 16
#define HD 128
#define SEQ 2048
#define HID 2048
#define NQKV 6144
#define BATCH 2

__device__ __forceinline__ ushort_t f2bf(float x) {
    unsigned u = __builtin_bit_cast(unsigned, x);
    u = (u + 0x7fffu + ((u >> 16) & 1u)) >> 16;
    return (ushort_t)u;
}

// async global->LDS, 16B per lane. LDS dest = wave-uniform base + lane*16.
__device__ __forceinline__ void gl2lds16(const ushort_t* g, ushort_t* l) {
    __builtin_amdgcn_global_load_lds(
        (__attribute__((address_space(1))) void*)(g),
        (__attribute__((address_space(3))) void*)(l), 16, 0, 0);
}

// ---------------------------------------------------------------------------
// fp32 -> bf16 elementwise (hidden states), 8 elems/thread
// ---------------------------------------------------------------------------
__global__ __launch_bounds__(256) void to_bf16(
    const float* __restrict__ x, ushort_t* __restrict__ y, int n8) {
    int i = blockIdx.x * 256 + threadIdx.x;
    if (i >= n8) return;
    float4 a0 = *(const float4*)(x + (size_t)i * 8);
    float4 a1 = *(const float4*)(x + (size_t)i * 8 + 4);
    union { ushort_t u[8]; uint4 v; } p;
    p.u[0]=f2bf(a0.x); p.u[1]=f2bf(a0.y); p.u[2]=f2bf(a0.z); p.u[3]=f2bf(a0.w);
    p.u[4]=f2bf(a1.x); p.u[5]=f2bf(a1.y); p.u[6]=f2bf(a1.z); p.u[7]=f2bf(a1.w);
    *(uint4*)(y + (size_t)i * 8) = p.v;
}

// ---------------------------------------------------------------------------
// Transpose + fp32->bf16: w [K][N] -> wT [N][K] bf16
// ---------------------------------------------------------------------------
__global__ __launch_bounds__(256) void transpose_to_bf16(
    const float* __restrict__ w, ushort_t* __restrict__ wT, int K, int N) {
    __shared__ float tile[32][33];
    int nb = blockIdx.x * 32, kb = blockIdx.y * 32;
    int tx = threadIdx.x, ty = threadIdx.y;  // 32 x 8
#pragma unroll
    for (int i = 0; i < 4; ++i) {
        int k = kb + ty + i * 8;
        tile[ty + i * 8][tx] = w[(size_t)k * N + nb + tx];
    }
    __syncthreads();
#pragma unroll
    for (int i = 0; i < 4; ++i) {
        int n = nb + ty + i * 8;
        wT[(size_t)n * K + kb + tx] = f2bf(tile[tx][ty + i * 8]);
    }
}

// ---------------------------------------------------------------------------
// bf16 transpose: v [bh][S][hd] -> vT [bh][hd][S], 32x32 tiles
// ---------------------------------------------------------------------------
__global__ __launch_bounds__(256) void transpose_v(
    const ushort_t* __restrict__ v, ushort_t* __restrict__ vT) {
    __shared__ ushort_t tile[32][33];
    const int bh = blockIdx.z;
    const int s0 = blockIdx.y * 32, d0 = blockIdx.x * 32;
    const int t = threadIdx.x, tx = t & 31, ty = t >> 5;
#pragma unroll
    for (int i = 0; i < 4; ++i)
        tile[ty + i * 8][tx] = v[((size_t)bh * SEQ + s0 + ty + i * 8) * HD + d0 + tx];
    __syncthreads();
#pragma unroll
    for (int i = 0; i < 4; ++i)
        vT[((size_t)bh * HD + d0 + ty + i * 8) * SEQ + s0 + tx] = tile[tx][ty + i * 8];
}

// ---------------------------------------------------------------------------
// m97-style GEMM core: 128x128 tile, BK=64, global_load_lds(16B) staging with
// XOR-swizzled chunk order. LDS[r][slot s] holds global k-chunk s^(r&7).
// ---------------------------------------------------------------------------
#define GEMM_KLOOP(A_, BT_)                                                     \
    const int t = threadIdx.x;                                                  \
    const int w = t >> 6, lane = t & 63, lm = lane & 15, lq = lane >> 4;        \
    const int wm = (w >> 1) * 64, wn = (w & 1) * 64;                            \
    const int lrow = lane >> 3, lsw = (lane & 7) ^ lrow;                        \
    f32x4 acc[4][4] = {};                                                       \
    const ushort_t* gA = A_ + (size_t)(mb + w * 32 + lrow) * HID + lsw * 8;     \
    const ushort_t* gB = BT_ + (size_t)(nb + w * 32 + lrow) * HID + lsw * 8;    \
    for (int kb = 0; kb < HID; kb += 64) {                                      \
        __syncthreads();                                                        \
        _Pragma("unroll")                                                       \
        for (int c = 0; c < 4; ++c) {                                           \
            gl2lds16(gA + (size_t)c * 8 * HID + kb, At + (w * 256 + c * 64) * 8); \
            gl2lds16(gB + (size_t)c * 8 * HID + kb, Bt + (w * 256 + c * 64) * 8); \
        }                                                                       \
        __syncthreads();                                                        \
        _Pragma("unroll")                                                       \
        for (int kc = 0; kc < 2; ++kc) {                                        \
            const int slot = (kc * 4 + lq) ^ (lm & 7);                          \
            bf16x8 af[4], bfr[4];                                               \
            _Pragma("unroll")                                                   \
            for (int mt = 0; mt < 4; ++mt)                                      \
                af[mt] = ((const bf16x8*)At)[(wm + mt * 16 + lm) * 8 + slot];   \
            _Pragma("unroll")                                                   \
            for (int nt = 0; nt < 4; ++nt)                                      \
                bfr[nt] = ((const bf16x8*)Bt)[(wn + nt * 16 + lm) * 8 + slot];  \
            _Pragma("unroll")                                                   \
            for (int mt = 0; mt < 4; ++mt)                                      \
                _Pragma("unroll")                                               \
                for (int nt = 0; nt < 4; ++nt)                                  \
                    acc[mt][nt] = __builtin_amdgcn_mfma_f32_16x16x32_bf16(      \
                        af[mt], bfr[nt], acc[mt][nt], 0, 0, 0);                 \
        }                                                                       \
    }

// GEMM 1: qkv = hidden(bf16) @ w_qkv + b_qkv; q,k,v -> [B,nh,S,hd] (coalesced)
__global__ __launch_bounds__(256) void gemm_qkv(
    const ushort_t* __restrict__ A, const ushort_t* __restrict__ BT,
    const float* __restrict__ bias,
    ushort_t* __restrict__ qbuf, ushort_t* __restrict__ kbuf,
    ushort_t* __restrict__ vbuf) {
    __shared__ ushort_t At[128 * 64];
    __shared__ ushort_t Bt[128 * 64];
    const int mb = blockIdx.x * 128;
    const int nb = blockIdx.y * 128;
    GEMM_KLOOP(A, BT)
#pragma unroll
    for (int mt = 0; mt < 4; ++mt)
#pragma unroll
        for (int nt = 0; nt < 4; ++nt)
#pragma unroll
            for (int r = 0; r < 4; ++r) {
                int m = mb + wm + mt * 16 + lq * 4 + r;
                int c = nb + wn + nt * 16 + lm;
                float val = acc[mt][nt][r] + bias[c];
                int sec = c >> 11;
                int h = (c >> 7) & 15;
                int d = c & 127;
                int b = m >> 11, s = m & 2047;
                size_t bh = (size_t)(b * NH + h);
                ushort_t* dst = (sec == 0) ? qbuf : (sec == 1) ? kbuf : vbuf;
                dst[(bh * SEQ + s) * HD + d] = f2bf(val);
            }
}

// GEMM 2: out = attn(bf16) @ w_proj + b_proj -> fp32
__global__ __launch_bounds__(256) void gemm_proj(
    const ushort_t* __restrict__ A, const ushort_t* __restrict__ BT,
    const float* __restrict__ bias, float* __restrict__ out) {
    __shared__ ushort_t At[128 * 64];
    __shared__ ushort_t Bt[128 * 64];
    const int mb = blockIdx.x * 128;
    const int nb = blockIdx.y * 128;
    GEMM_KLOOP(A, BT)
#pragma unroll
    for (int mt = 0; mt < 4; ++mt)
#pragma unroll
        for (int nt = 0; nt < 4; ++nt)
#pragma unroll
            for (int r = 0; r < 4; ++r) {
                int m = mb + wm + mt * 16 + lq * 4 + r;
                int c = nb + wn + nt * 16 + lm;
                out[(size_t)m * HID + c] = acc[mt][nt][r] + bias[c];
            }
}

// ---------------------------------------------------------------------------
// Flash attention, S^T = K Q^T formulation. Grid 1024: one 64-row q-tile per
// block, qt DESCENDING (LPT dynamic balance), 3 blocks/CU (LDS 41KB).
// 64-key iterations; K and V^T staged via global_load_lds(16B) with
// XOR-swizzled chunks (unpadded, <=2-way banks). Q frags direct from global.
// ---------------------------------------------------------------------------
__global__ __launch_bounds__(256) void attn_kernel(
    const ushort_t* __restrict__ qb, const ushort_t* __restrict__ kbuf,
    const ushort_t* __restrict__ vT, ushort_t* __restrict__ ob) {
    __shared__ ushort_t Ks[64 * 128];   // [key][d] swizzled 16B chunks
    __shared__ ushort_t Vs[128 * 64];   // [d][key] swizzled 16B chunks
    __shared__ ushort_t Ps[4][16 * 72]; // per-wave P, row stride 72 (16B-aligned)

    const int bid = blockIdx.x;
    const int qt = 31 - (bid >> 5);   // big tiles dispatched first
    const int bh = bid & 31;
    const int qbase = qt * 64;
    const int t = threadIdx.x, w = t >> 6, lane = t & 63;
    const int lm = lane & 15, lq = lane >> 4;

    const ushort_t* Qg = qb + (size_t)bh * SEQ * HD;
    const ushort_t* Kg = kbuf + (size_t)bh * SEQ * HD;
    const ushort_t* Vg = vT + (size_t)bh * HD * SEQ;

    const float LOG2E = 1.44269504f;
    const int h = bh & 15;
    const float slope2 = exp2f(-0.5f * (float)(h + 1)) * LOG2E;
    const float scale2 = (1.0f / 128.0f) * LOG2E;

    const int qg = qbase + w * 16 + lm;  // this lane's q row

    // Q fragments direct from global (B-operand layout)
    bf16x8 qf[4];
#pragma unroll
    for (int kc = 0; kc < 4; ++kc) {
        uint4 qv = *(const uint4*)(Qg + (size_t)qg * HD + kc * 32 + lq * 8);
        qf[kc] = __builtin_bit_cast(bf16x8, qv);
    }

    float foff[4][4];
    int koff[4][4];
#pragma unroll
    for (int mt = 0; mt < 4; ++mt)
#pragma unroll
        for (int r = 0; r < 4; ++r) {
            koff[mt][r] = mt * 16 + lq * 4 + r;
            foff[mt][r] = slope2 * (float)koff[mt][r];
        }

    float mrow = -1e30f, lrow = 0.0f;
    f32x4 O[8] = {};
    const int nkt = qt + 1;

    for (int kt = 0; kt < nkt; ++kt) {
        __syncthreads();  // prev iteration's compute done
        // stage K [64][128] and V^T [128][64] via async DMA, swizzled
        {
            const ushort_t* Kt = Kg + (size_t)kt * 64 * HD;
#pragma unroll
            for (int i = 0; i < 4; ++i) {
                int ci = i * 256 + t;
                int kr = ci >> 4, ks = ci & 15;
                int kcg = (ks & 8) | ((ks & 7) ^ (kr & 7));
                gl2lds16(Kt + (size_t)kr * HD + kcg * 8, Ks + (i * 256 + w * 64) * 8);
                int vr = ci >> 3, vs = ci & 7;
                int vcg = vs ^ (vr & 7);
                gl2lds16(Vg + (size_t)vr * SEQ + kt * 64 + vcg * 8, Vs + (i * 256 + w * 64) * 8);
            }
        }
        __syncthreads();  // staging visible

        // S^T = K Q^T : per wave 64 keys x 16 q
        f32x4 sacc[4] = {};
#pragma unroll
        for (int kc = 0; kc < 4; ++kc) {
            const int slot = ((kc * 4 + lq) & 8) | (((kc * 4 + lq) & 7) ^ (lm & 7));
#pragma unroll
            for (int mt = 0; mt < 4; ++mt) {
                bf16x8 bk = *(const bf16x8*)&Ks[((mt * 16 + lm) * 16 + slot) * 8];
                sacc[mt] = __builtin_amdgcn_mfma_f32_16x16x32_bf16(bk, qf[kc], sacc[mt], 0, 0, 0);
            }
        }

        // scores (log2 domain); mask only on the diagonal tile
        const float sbase = slope2 * (float)(kt * 64 - qg);
        float sc[4][4];
        if (kt == qt) {
#pragma unroll
            for (int mt = 0; mt < 4; ++mt)
#pragma unroll
                for (int r = 0; r < 4; ++r) {
                    float s = sacc[mt][r] * scale2 + (sbase + foff[mt][r]);
                    sc[mt][r] = (kt * 64 + koff[mt][r] <= qg) ? s : -3e38f;
                }
        } else {
#pragma unroll
            for (int mt = 0; mt < 4; ++mt)
#pragma unroll
                for (int r = 0; r < 4; ++r)
                    sc[mt][r] = sacc[mt][r] * scale2 + (sbase + foff[mt][r]);
        }

        // row max: 15 in-lane + 2 shuffles
        float tm = sc[0][0];
#pragma unroll
        for (int mt = 0; mt < 4; ++mt)
#pragma unroll
            for (int r = 0; r < 4; ++r) tm = fmaxf(tm, sc[mt][r]);
        tm = fmaxf(tm, __shfl_xor(tm, 16));
        tm = fmaxf(tm, __shfl_xor(tm, 32));
        float mnew = fmaxf(mrow, tm);
        float alpha = __builtin_amdgcn_exp2f(mrow - mnew);
        mrow = mnew;

        // p = exp2(sc - m) -> Ps[q][key], sum
        float psum = 0.0f;
#pragma unroll
        for (int mt = 0; mt < 4; ++mt) {
            float p0 = __builtin_amdgcn_exp2f(sc[mt][0] - mnew);
            float p1 = __builtin_amdgcn_exp2f(sc[mt][1] - mnew);
            float p2 = __builtin_amdgcn_exp2f(sc[mt][2] - mnew);
            float p3 = __builtin_amdgcn_exp2f(sc[mt][3] - mnew);
            psum += (p0 + p1) + (p2 + p3);
            uint2 wv;
            wv.x = ((unsigned)f2bf(p1) << 16) | f2bf(p0);
            wv.y = ((unsigned)f2bf(p3) << 16) | f2bf(p2);
            *(uint2*)&Ps[w][lm * 72 + mt * 16 + lq * 4] = wv;
        }
        psum += __shfl_xor(psum, 16);
        psum += __shfl_xor(psum, 32);
        lrow = lrow * alpha + psum;

        // rescale O (O row q = lq*4+r; alpha lives at lane q = lm)
        float av[4];
#pragma unroll
        for (int r = 0; r < 4; ++r) av[r] = __shfl(alpha, lq * 4 + r);
#pragma unroll
        for (int nt = 0; nt < 8; ++nt)
#pragma unroll
            for (int r = 0; r < 4; ++r) O[nt][r] *= av[r];

        // PV: A = P (q=lane&15), B = V^T (swizzled)
        asm volatile("s_waitcnt lgkmcnt(0)" ::: "memory");
#pragma unroll
        for (int kc2 = 0; kc2 < 2; ++kc2) {
            bf16x8 ap = *(const bf16x8*)&Ps[w][lm * 72 + kc2 * 32 + lq * 8];
            const int slot = (kc2 * 4 + lq) ^ (lm & 7);
#pragma unroll
            for (int nt = 0; nt < 8; ++nt) {
                bf16x8 bv = *(const bf16x8*)&Vs[((nt * 16 + lm) * 8 + slot) * 8];
                O[nt] = __builtin_amdgcn_mfma_f32_16x16x32_bf16(ap, bv, O[nt], 0, 0, 0);
            }
        }
    }

    // epilogue
    float lb[4];
#pragma unroll
    for (int r = 0; r < 4; ++r)
        lb[r] = __builtin_amdgcn_rcpf(__shfl(lrow, lq * 4 + r));
    const int b = bh >> 4;
#pragma unroll
    for (int nt = 0; nt < 8; ++nt)
#pragma unroll
        for (int r = 0; r < 4; ++r) {
            int s = qbase + w * 16 + lq * 4 + r;
            int d = nt * 16 + lm;
            ob[((size_t)(b * SEQ + s)) * HID + h * HD + d] = f2bf(O[nt][r] * lb[r]);
        }
}

// ---------------------------------------------------------------------------
extern "C" void kernel_launch(void* const* d_in, const int* in_sizes, int n_in,
                              void* d_out, int out_size, void* d_ws, size_t ws_size,
                              hipStream_t stream) {
    const float* hidden = (const float*)d_in[0];
    const float* w_qkv = (const float*)d_in[1];
    const float* b_qkv = (const float*)d_in[2];
    const float* w_proj = (const float*)d_in[3];
    const float* b_proj = (const float*)d_in[4];
    float* out = (float*)d_out;

    char* ws = (char*)d_ws;
    size_t off = 0;
    ushort_t* wqkvT = (ushort_t*)(ws + off); off += (size_t)NQKV * HID * 2;
    ushort_t* wprojT = (ushort_t*)(ws + off); off += (size_t)HID * HID * 2;
    ushort_t* hbf = (ushort_t*)(ws + off); off += (size_t)BATCH * SEQ * HID * 2;
    ushort_t* qw = (ushort_t*)(ws + off); off += (size_t)BATCH * NH * SEQ * HD * 2;
    ushort_t* kw = (ushort_t*)(ws + off); off += (size_t)BATCH * NH * SEQ * HD * 2;
    ushort_t* vw = (ushort_t*)(ws + off); off += (size_t)BATCH * NH * SEQ * HD * 2;
    ushort_t* vTw = (ushort_t*)(ws + off); off += (size_t)BATCH * NH * SEQ * HD * 2;
    ushort_t* attnw = (ushort_t*)(ws + off); off += (size_t)BATCH * SEQ * HID * 2;

    to_bf16<<<dim3(BATCH * SEQ * HID / 8 / 256), 256, 0, stream>>>(
        hidden, hbf, BATCH * SEQ * HID / 8);
    transpose_to_bf16<<<dim3(NQKV / 32, HID / 32), dim3(32, 8), 0, stream>>>(
        w_qkv, wqkvT, HID, NQKV);
    transpose_to_bf16<<<dim3(HID / 32, HID / 32), dim3(32, 8), 0, stream>>>(
        w_proj, wprojT, HID, HID);

    gemm_qkv<<<dim3(BATCH * SEQ / 128, NQKV / 128), 256, 0, stream>>>(
        hbf, wqkvT, b_qkv, qw, kw, vw);

    transpose_v<<<dim3(HD / 32, SEQ / 32, BATCH * NH), 256, 0, stream>>>(vw, vTw);

    attn_kernel<<<dim3(BATCH * NH * 32), 256, 0, stream>>>(qw, kw, vTw, attnw);

    gemm_proj<<<dim3(BATCH * SEQ / 128, HID / 128), 256, 0, stream>>>(
        attnw, wprojT, b_proj, out);
}

// Round 5
// 376.489 us; speedup vs baseline: 2.2363x; 1.0044x over previous
//
#include <hip/hip_runtime.h>
#include <hip/hip_bf16.h>

typedef short bf16x8 __attribute__((ext_vector_type(8)));
typedef float f32x4 __attribute__((ext_vector_type(4)));
typedef unsigned short ushort_t;

#define NH 16
#define HD 128
#define SEQ 2048
#define HID 2048
#define NQKV 6144
#define BATCH 2

__device__ __forceinline__ ushort_t f2bf(float x) {
    unsigned u = __builtin_bit_cast(unsigned, x);
    u = (u + 0x7fffu + ((u >> 16) & 1u)) >> 16;
    return (ushort_t)u;
}

// async global->LDS, 16B per lane. LDS dest = wave-uniform base + lane*16.
__device__ __forceinline__ void gl2lds16(const ushort_t* g, ushort_t* l) {
    __builtin_amdgcn_global_load_lds(
        (__attribute__((address_space(1))) void*)(g),
        (__attribute__((address_space(3))) void*)(l), 16, 0, 0);
}

// ---------------------------------------------------------------------------
// fp32 -> bf16 elementwise (hidden states), 8 elems/thread
// ---------------------------------------------------------------------------
__global__ __launch_bounds__(256) void to_bf16(
    const float* __restrict__ x, ushort_t* __restrict__ y, int n8) {
    int i = blockIdx.x * 256 + threadIdx.x;
    if (i >= n8) return;
    float4 a0 = *(const float4*)(x + (size_t)i * 8);
    float4 a1 = *(const float4*)(x + (size_t)i * 8 + 4);
    union { ushort_t u[8]; uint4 v; } p;
    p.u[0]=f2bf(a0.x); p.u[1]=f2bf(a0.y); p.u[2]=f2bf(a0.z); p.u[3]=f2bf(a0.w);
    p.u[4]=f2bf(a1.x); p.u[5]=f2bf(a1.y); p.u[6]=f2bf(a1.z); p.u[7]=f2bf(a1.w);
    *(uint4*)(y + (size_t)i * 8) = p.v;
}

// ---------------------------------------------------------------------------
// Transpose + fp32->bf16: w [K][N] -> wT [N][K] bf16
// ---------------------------------------------------------------------------
__global__ __launch_bounds__(256) void transpose_to_bf16(
    const float* __restrict__ w, ushort_t* __restrict__ wT, int K, int N) {
    __shared__ float tile[32][33];
    int nb = blockIdx.x * 32, kb = blockIdx.y * 32;
    int tx = threadIdx.x, ty = threadIdx.y;  // 32 x 8
#pragma unroll
    for (int i = 0; i < 4; ++i) {
        int k = kb + ty + i * 8;
        tile[ty + i * 8][tx] = w[(size_t)k * N + nb + tx];
    }
    __syncthreads();
#pragma unroll
    for (int i = 0; i < 4; ++i) {
        int n = nb + ty + i * 8;
        wT[(size_t)n * K + kb + tx] = f2bf(tile[tx][ty + i * 8]);
    }
}

// ---------------------------------------------------------------------------
// bf16 transpose: v [bh][S][hd] -> vT [bh][hd][S], 32x32 tiles
// ---------------------------------------------------------------------------
__global__ __launch_bounds__(256) void transpose_v(
    const ushort_t* __restrict__ v, ushort_t* __restrict__ vT) {
    __shared__ ushort_t tile[32][33];
    const int bh = blockIdx.z;
    const int s0 = blockIdx.y * 32, d0 = blockIdx.x * 32;
    const int t = threadIdx.x, tx = t & 31, ty = t >> 5;
#pragma unroll
    for (int i = 0; i < 4; ++i)
        tile[ty + i * 8][tx] = v[((size_t)bh * SEQ + s0 + ty + i * 8) * HD + d0 + tx];
    __syncthreads();
#pragma unroll
    for (int i = 0; i < 4; ++i)
        vT[((size_t)bh * HD + d0 + ty + i * 8) * SEQ + s0 + tx] = tile[tx][ty + i * 8];
}

// ---------------------------------------------------------------------------
// m97-style GEMM core: 128x128 tile, BK=64, global_load_lds(16B) staging with
// XOR-swizzled chunk order. LDS[r][slot s] holds global k-chunk s^(r&7).
// ---------------------------------------------------------------------------
#define GEMM_KLOOP(A_, BT_)                                                     \
    const int t = threadIdx.x;                                                  \
    const int w = t >> 6, lane = t & 63, lm = lane & 15, lq = lane >> 4;        \
    const int wm = (w >> 1) * 64, wn = (w & 1) * 64;                            \
    const int lrow = lane >> 3, lsw = (lane & 7) ^ lrow;                        \
    f32x4 acc[4][4] = {};                                                       \
    const ushort_t* gA = A_ + (size_t)(mb + w * 32 + lrow) * HID + lsw * 8;     \
    const ushort_t* gB = BT_ + (size_t)(nb + w * 32 + lrow) * HID + lsw * 8;    \
    for (int kb = 0; kb < HID; kb += 64) {                                      \
        __syncthreads();                                                        \
        _Pragma("unroll")                                                       \
        for (int c = 0; c < 4; ++c) {                                           \
            gl2lds16(gA + (size_t)c * 8 * HID + kb, At + (w * 256 + c * 64) * 8); \
            gl2lds16(gB + (size_t)c * 8 * HID + kb, Bt + (w * 256 + c * 64) * 8); \
        }                                                                       \
        __syncthreads();                                                        \
        _Pragma("unroll")                                                       \
        for (int kc = 0; kc < 2; ++kc) {                                        \
            const int slot = (kc * 4 + lq) ^ (lm & 7);                          \
            bf16x8 af[4], bfr[4];                                               \
            _Pragma("unroll")                                                   \
            for (int mt = 0; mt < 4; ++mt)                                      \
                af[mt] = ((const bf16x8*)At)[(wm + mt * 16 + lm) * 8 + slot];   \
            _Pragma("unroll")                                                   \
            for (int nt = 0; nt < 4; ++nt)                                      \
                bfr[nt] = ((const bf16x8*)Bt)[(wn + nt * 16 + lm) * 8 + slot];  \
            _Pragma("unroll")                                                   \
            for (int mt = 0; mt < 4; ++mt)                                      \
                _Pragma("unroll")                                               \
                for (int nt = 0; nt < 4; ++nt)                                  \
                    acc[mt][nt] = __builtin_amdgcn_mfma_f32_16x16x32_bf16(      \
                        af[mt], bfr[nt], acc[mt][nt], 0, 0, 0);                 \
        }                                                                       \
    }

// GEMM 1: qkv = hidden(bf16) @ w_qkv + b_qkv; q,k,v -> [B,nh,S,hd] (coalesced)
__global__ __launch_bounds__(256) void gemm_qkv(
    const ushort_t* __restrict__ A, const ushort_t* __restrict__ BT,
    const float* __restrict__ bias,
    ushort_t* __restrict__ qbuf, ushort_t* __restrict__ kbuf,
    ushort_t* __restrict__ vbuf) {
    __shared__ ushort_t At[128 * 64];
    __shared__ ushort_t Bt[128 * 64];
    const int mb = blockIdx.x * 128;
    const int nb = blockIdx.y * 128;
    GEMM_KLOOP(A, BT)
#pragma unroll
    for (int mt = 0; mt < 4; ++mt)
#pragma unroll
        for (int nt = 0; nt < 4; ++nt)
#pragma unroll
            for (int r = 0; r < 4; ++r) {
                int m = mb + wm + mt * 16 + lq * 4 + r;
                int c = nb + wn + nt * 16 + lm;
                float val = acc[mt][nt][r] + bias[c];
                int sec = c >> 11;
                int h = (c >> 7) & 15;
                int d = c & 127;
                int b = m >> 11, s = m & 2047;
                size_t bh = (size_t)(b * NH + h);
                ushort_t* dst = (sec == 0) ? qbuf : (sec == 1) ? kbuf : vbuf;
                dst[(bh * SEQ + s) * HD + d] = f2bf(val);
            }
}

// GEMM 2: out = attn(bf16) @ w_proj + b_proj -> fp32
__global__ __launch_bounds__(256) void gemm_proj(
    const ushort_t* __restrict__ A, const ushort_t* __restrict__ BT,
    const float* __restrict__ bias, float* __restrict__ out) {
    __shared__ ushort_t At[128 * 64];
    __shared__ ushort_t Bt[128 * 64];
    const int mb = blockIdx.x * 128;
    const int nb = blockIdx.y * 128;
    GEMM_KLOOP(A, BT)
#pragma unroll
    for (int mt = 0; mt < 4; ++mt)
#pragma unroll
        for (int nt = 0; nt < 4; ++nt)
#pragma unroll
            for (int r = 0; r < 4; ++r) {
                int m = mb + wm + mt * 16 + lq * 4 + r;
                int c = nb + wn + nt * 16 + lm;
                out[(size_t)m * HID + c] = acc[mt][nt][r] + bias[c];
            }
}

// ---------------------------------------------------------------------------
// Flash attention, S^T = K Q^T. Grid 1024, qt descending (LPT). Double-
// buffered K/V staging via global_load_lds with ONE barrier per iteration:
//   sync -> issue DMA(kt+1 -> buf^1) -> compute(buf)
// The compiler's vmcnt(0)-before-barrier then drains a DMA that had the whole
// previous compute to fly -> staging latency hidden. 74KB LDS, 2 blocks/CU.
// ---------------------------------------------------------------------------
__global__ __launch_bounds__(256) void attn_kernel(
    const ushort_t* __restrict__ qb, const ushort_t* __restrict__ kbuf,
    const ushort_t* __restrict__ vT, ushort_t* __restrict__ ob) {
    __shared__ ushort_t Ks[2][64 * 128];   // [key][d] swizzled 16B chunks
    __shared__ ushort_t Vs[2][128 * 64];   // [d][key] swizzled 16B chunks
    __shared__ ushort_t Ps[4][16 * 72];    // per-wave P, row stride 72

    const int bid = blockIdx.x;
    const int qt = 31 - (bid >> 5);   // big tiles dispatched first
    const int bh = bid & 31;
    const int qbase = qt * 64;
    const int t = threadIdx.x, w = t >> 6, lane = t & 63;
    const int lm = lane & 15, lq = lane >> 4;

    const ushort_t* Qg = qb + (size_t)bh * SEQ * HD;
    const ushort_t* Kg = kbuf + (size_t)bh * SEQ * HD;
    const ushort_t* Vg = vT + (size_t)bh * HD * SEQ;

    const float LOG2E = 1.44269504f;
    const int h = bh & 15;
    const float slope2 = exp2f(-0.5f * (float)(h + 1)) * LOG2E;
    const float scale2 = (1.0f / 128.0f) * LOG2E;

    const int qg = qbase + w * 16 + lm;  // this lane's q row

    // Q fragments direct from global (B-operand layout)
    bf16x8 qf[4];
#pragma unroll
    for (int kc = 0; kc < 4; ++kc) {
        uint4 qv = *(const uint4*)(Qg + (size_t)qg * HD + kc * 32 + lq * 8);
        qf[kc] = __builtin_bit_cast(bf16x8, qv);
    }

    float foff[4][4];
    int koff[4][4];
#pragma unroll
    for (int mt = 0; mt < 4; ++mt)
#pragma unroll
        for (int r = 0; r < 4; ++r) {
            koff[mt][r] = mt * 16 + lq * 4 + r;
            foff[mt][r] = slope2 * (float)koff[mt][r];
        }

    // staging: 1024 16B-chunks each for K and V, swizzled
    const int ci0 = t;
    auto stage = [&](int kt, int buf) {
        const ushort_t* Kt = Kg + (size_t)kt * 64 * HD;
#pragma unroll
        for (int i = 0; i < 4; ++i) {
            int ci = i * 256 + ci0;
            int kr = ci >> 4, ks = ci & 15;
            int kcg = (ks & 8) | ((ks & 7) ^ (kr & 7));
            gl2lds16(Kt + (size_t)kr * HD + kcg * 8, Ks[buf] + (i * 256 + w * 64) * 8);
            int vr = ci >> 3, vs = ci & 7;
            int vcg = vs ^ (vr & 7);
            gl2lds16(Vg + (size_t)vr * SEQ + kt * 64 + vcg * 8, Vs[buf] + (i * 256 + w * 64) * 8);
        }
    };

    float mrow = -1e30f, lrow = 0.0f;
    f32x4 O[8] = {};
    const int nkt = qt + 1;

    stage(0, 0);

    for (int kt = 0; kt < nkt; ++kt) {
        __syncthreads();  // drains DMA(kt); orders vs prev compute
        if (kt + 1 < nkt) stage(kt + 1, (kt + 1) & 1);
        const ushort_t* Kb = Ks[kt & 1];
        const ushort_t* Vb = Vs[kt & 1];

        // S^T = K Q^T : per wave 64 keys x 16 q
        f32x4 sacc[4] = {};
#pragma unroll
        for (int kc = 0; kc < 4; ++kc) {
            const int slot = ((kc * 4 + lq) & 8) | (((kc * 4 + lq) & 7) ^ (lm & 7));
#pragma unroll
            for (int mt = 0; mt < 4; ++mt) {
                bf16x8 bk = *(const bf16x8*)&Kb[((mt * 16 + lm) * 16 + slot) * 8];
                sacc[mt] = __builtin_amdgcn_mfma_f32_16x16x32_bf16(bk, qf[kc], sacc[mt], 0, 0, 0);
            }
        }

        // scores (log2 domain); mask only on the diagonal tile
        const float sbase = slope2 * (float)(kt * 64 - qg);
        float sc[4][4];
        if (kt == qt) {
#pragma unroll
            for (int mt = 0; mt < 4; ++mt)
#pragma unroll
                for (int r = 0; r < 4; ++r) {
                    float s = sacc[mt][r] * scale2 + (sbase + foff[mt][r]);
                    sc[mt][r] = (kt * 64 + koff[mt][r] <= qg) ? s : -3e38f;
                }
        } else {
#pragma unroll
            for (int mt = 0; mt < 4; ++mt)
#pragma unroll
                for (int r = 0; r < 4; ++r)
                    sc[mt][r] = sacc[mt][r] * scale2 + (sbase + foff[mt][r]);
        }

        // row max: 15 in-lane + 2 shuffles
        float tm = sc[0][0];
#pragma unroll
        for (int mt = 0; mt < 4; ++mt)
#pragma unroll
            for (int r = 0; r < 4; ++r) tm = fmaxf(tm, sc[mt][r]);
        tm = fmaxf(tm, __shfl_xor(tm, 16));
        tm = fmaxf(tm, __shfl_xor(tm, 32));
        float mnew = fmaxf(mrow, tm);
        float alpha = __builtin_amdgcn_exp2f(mrow - mnew);
        mrow = mnew;

        // p = exp2(sc - m) -> Ps[q][key], sum
        float psum = 0.0f;
#pragma unroll
        for (int mt = 0; mt < 4; ++mt) {
            float p0 = __builtin_amdgcn_exp2f(sc[mt][0] - mnew);
            float p1 = __builtin_amdgcn_exp2f(sc[mt][1] - mnew);
            float p2 = __builtin_amdgcn_exp2f(sc[mt][2] - mnew);
            float p3 = __builtin_amdgcn_exp2f(sc[mt][3] - mnew);
            psum += (p0 + p1) + (p2 + p3);
            uint2 wv;
            wv.x = ((unsigned)f2bf(p1) << 16) | f2bf(p0);
            wv.y = ((unsigned)f2bf(p3) << 16) | f2bf(p2);
            *(uint2*)&Ps[w][lm * 72 + mt * 16 + lq * 4] = wv;
        }
        psum += __shfl_xor(psum, 16);
        psum += __shfl_xor(psum, 32);
        lrow = lrow * alpha + psum;

        // rescale O (O row q = lq*4+r; alpha lives at lane q = lm)
        float av[4];
#pragma unroll
        for (int r = 0; r < 4; ++r) av[r] = __shfl(alpha, lq * 4 + r);
#pragma unroll
        for (int nt = 0; nt < 8; ++nt)
#pragma unroll
            for (int r = 0; r < 4; ++r) O[nt][r] *= av[r];

        // PV: A = P (q=lane&15), B = V^T (swizzled)
        asm volatile("s_waitcnt lgkmcnt(0)" ::: "memory");
#pragma unroll
        for (int kc2 = 0; kc2 < 2; ++kc2) {
            bf16x8 ap = *(const bf16x8*)&Ps[w][lm * 72 + kc2 * 32 + lq * 8];
            const int slot = (kc2 * 4 + lq) ^ (lm & 7);
#pragma unroll
            for (int nt = 0; nt < 8; ++nt) {
                bf16x8 bv = *(const bf16x8*)&Vb[((nt * 16 + lm) * 8 + slot) * 8];
                O[nt] = __builtin_amdgcn_mfma_f32_16x16x32_bf16(ap, bv, O[nt], 0, 0, 0);
            }
        }
        // no trailing barrier: next iteration's sync orders LDS reuse
    }

    // epilogue
    float lb[4];
#pragma unroll
    for (int r = 0; r < 4; ++r)
        lb[r] = __builtin_amdgcn_rcpf(__shfl(lrow, lq * 4 + r));
    const int b = bh >> 4;
#pragma unroll
    for (int nt = 0; nt < 8; ++nt)
#pragma unroll
        for (int r = 0; r < 4; ++r) {
            int s = qbase + w * 16 + lq * 4 + r;
            int d = nt * 16 + lm;
            ob[((size_t)(b * SEQ + s)) * HID + h * HD + d] = f2bf(O[nt][r] * lb[r]);
        }
}

// ---------------------------------------------------------------------------
extern "C" void kernel_launch(void* const* d_in, const int* in_sizes, int n_in,
                              void* d_out, int out_size, void* d_ws, size_t ws_size,
                              hipStream_t stream) {
    const float* hidden = (const float*)d_in[0];
    const float* w_qkv = (const float*)d_in[1];
    const float* b_qkv = (const float*)d_in[2];
    const float* w_proj = (const float*)d_in[3];
    const float* b_proj = (const float*)d_in[4];
    float* out = (float*)d_out;

    char* ws = (char*)d_ws;
    size_t off = 0;
    ushort_t* wqkvT = (ushort_t*)(ws + off); off += (size_t)NQKV * HID * 2;
    ushort_t* wprojT = (ushort_t*)(ws + off); off += (size_t)HID * HID * 2;
    ushort_t* hbf = (ushort_t*)(ws + off); off += (size_t)BATCH * SEQ * HID * 2;
    ushort_t* qw = (ushort_t*)(ws + off); off += (size_t)BATCH * NH * SEQ * HD * 2;
    ushort_t* kw = (ushort_t*)(ws + off); off += (size_t)BATCH * NH * SEQ * HD * 2;
    ushort_t* vw = (ushort_t*)(ws + off); off += (size_t)BATCH * NH * SEQ * HD * 2;
    ushort_t* vTw = (ushort_t*)(ws + off); off += (size_t)BATCH * NH * SEQ * HD * 2;
    ushort_t* attnw = (ushort_t*)(ws + off); off += (size_t)BATCH * SEQ * HID * 2;

    to_bf16<<<dim3(BATCH * SEQ * HID / 8 / 256), 256, 0, stream>>>(
        hidden, hbf, BATCH * SEQ * HID / 8);
    transpose_to_bf16<<<dim3(NQKV / 32, HID / 32), dim3(32, 8), 0, stream>>>(
        w_qkv, wqkvT, HID, NQKV);
    transpose_to_bf16<<<dim3(HID / 32, HID / 32), dim3(32, 8), 0, stream>>>(
        w_proj, wprojT, HID, HID);

    gemm_qkv<<<dim3(BATCH * SEQ / 128, NQKV / 128), 256, 0, stream>>>(
        hbf, wqkvT, b_qkv, qw, kw, vw);

    transpose_v<<<dim3(HD / 32, SEQ / 32, BATCH * NH), 256, 0, stream>>>(vw, vTw);

    attn_kernel<<<dim3(BATCH * NH * 32), 256, 0, stream>>>(qw, kw, vTw, attnw);

    gemm_proj<<<dim3(BATCH * SEQ / 128, HID / 128), 256, 0, stream>>>(
        attnw, wprojT, b_proj, out);
}

// Round 6
// 366.464 us; speedup vs baseline: 2.2975x; 1.0274x over previous
//
#include <hip/hip_runtime.h>
#include <hip/hip_bf16.h>

typedef short bf16x8 __attribute__((ext_vector_type(8)));
typedef float f32x4 __attribute__((ext_vector_type(4)));
typedef unsigned short ushort_t;

#define NH 16
#define HD 128
#define SEQ 2048
#define HID 2048
#define NQKV 6144
#define BATCH 2

__device__ __forceinline__ ushort_t f2bf(float x) {
    unsigned u = __builtin_bit_cast(unsigned, x);
    u = (u + 0x7fffu + ((u >> 16) & 1u)) >> 16;
    return (ushort_t)u;
}

// async global->LDS, 16B per lane. LDS dest = wave-uniform base + lane*16.
__device__ __forceinline__ void gl2lds16(const ushort_t* g, ushort_t* l) {
    __builtin_amdgcn_global_load_lds(
        (__attribute__((address_space(1))) void*)(g),
        (__attribute__((address_space(3))) void*)(l), 16, 0, 0);
}

// ---------------------------------------------------------------------------
// fp32 -> bf16 elementwise (hidden states), 8 elems/thread
// ---------------------------------------------------------------------------
__global__ __launch_bounds__(256) void to_bf16(
    const float* __restrict__ x, ushort_t* __restrict__ y, int n8) {
    int i = blockIdx.x * 256 + threadIdx.x;
    if (i >= n8) return;
    float4 a0 = *(const float4*)(x + (size_t)i * 8);
    float4 a1 = *(const float4*)(x + (size_t)i * 8 + 4);
    union { ushort_t u[8]; uint4 v; } p;
    p.u[0]=f2bf(a0.x); p.u[1]=f2bf(a0.y); p.u[2]=f2bf(a0.z); p.u[3]=f2bf(a0.w);
    p.u[4]=f2bf(a1.x); p.u[5]=f2bf(a1.y); p.u[6]=f2bf(a1.z); p.u[7]=f2bf(a1.w);
    *(uint4*)(y + (size_t)i * 8) = p.v;
}

// ---------------------------------------------------------------------------
// Transpose + fp32->bf16: w [K][N] -> wT [N][K] bf16
// ---------------------------------------------------------------------------
__global__ __launch_bounds__(256) void transpose_to_bf16(
    const float* __restrict__ w, ushort_t* __restrict__ wT, int K, int N) {
    __shared__ float tile[32][33];
    int nb = blockIdx.x * 32, kb = blockIdx.y * 32;
    int tx = threadIdx.x, ty = threadIdx.y;  // 32 x 8
#pragma unroll
    for (int i = 0; i < 4; ++i) {
        int k = kb + ty + i * 8;
        tile[ty + i * 8][tx] = w[(size_t)k * N + nb + tx];
    }
    __syncthreads();
#pragma unroll
    for (int i = 0; i < 4; ++i) {
        int n = nb + ty + i * 8;
        wT[(size_t)n * K + kb + tx] = f2bf(tile[tx][ty + i * 8]);
    }
}

// ---------------------------------------------------------------------------
// m97-style GEMM core: 128x128 tile, BK=64, global_load_lds(16B) staging with
// XOR-swizzled chunk order. LDS[r][slot s] holds global k-chunk s^(r&7).
// ---------------------------------------------------------------------------
#define GEMM_KLOOP(A_, BT_)                                                     \
    const int t = threadIdx.x;                                                  \
    const int w = t >> 6, lane = t & 63, lm = lane & 15, lq = lane >> 4;        \
    const int wm = (w >> 1) * 64, wn = (w & 1) * 64;                            \
    const int lrow = lane >> 3, lsw = (lane & 7) ^ lrow;                        \
    f32x4 acc[4][4] = {};                                                       \
    const ushort_t* gA = A_ + (size_t)(mb + w * 32 + lrow) * HID + lsw * 8;     \
    const ushort_t* gB = BT_ + (size_t)(nb + w * 32 + lrow) * HID + lsw * 8;    \
    for (int kb = 0; kb < HID; kb += 64) {                                      \
        __syncthreads();                                                        \
        _Pragma("unroll")                                                       \
        for (int c = 0; c < 4; ++c) {                                           \
            gl2lds16(gA + (size_t)c * 8 * HID + kb, At + (w * 256 + c * 64) * 8); \
            gl2lds16(gB + (size_t)c * 8 * HID + kb, Bt + (w * 256 + c * 64) * 8); \
        }                                                                       \
        __syncthreads();                                                        \
        _Pragma("unroll")                                                       \
        for (int kc = 0; kc < 2; ++kc) {                                        \
            const int slot = (kc * 4 + lq) ^ (lm & 7);                          \
            bf16x8 af[4], bfr[4];                                               \
            _Pragma("unroll")                                                   \
            for (int mt = 0; mt < 4; ++mt)                                      \
                af[mt] = ((const bf16x8*)At)[(wm + mt * 16 + lm) * 8 + slot];   \
            _Pragma("unroll")                                                   \
            for (int nt = 0; nt < 4; ++nt)                                      \
                bfr[nt] = ((const bf16x8*)Bt)[(wn + nt * 16 + lm) * 8 + slot];  \
            _Pragma("unroll")                                                   \
            for (int mt = 0; mt < 4; ++mt)                                      \
                _Pragma("unroll")                                               \
                for (int nt = 0; nt < 4; ++nt)                                  \
                    acc[mt][nt] = __builtin_amdgcn_mfma_f32_16x16x32_bf16(      \
                        af[mt], bfr[nt], acc[mt][nt], 0, 0, 0);                 \
        }                                                                       \
    }

// ---------------------------------------------------------------------------
// GEMM 1: qkv = hidden(bf16) @ w_qkv + b_qkv
// q,k -> [B,nh,S,hd]; v -> vT [B,nh,hd,S] via in-LDS transpose (tile = 128 s
// x one head's 128 d), coalesced 16B writes.
// ---------------------------------------------------------------------------
__global__ __launch_bounds__(256) void gemm_qkv(
    const ushort_t* __restrict__ A, const ushort_t* __restrict__ BT,
    const float* __restrict__ bias,
    ushort_t* __restrict__ qbuf, ushort_t* __restrict__ kbuf,
    ushort_t* __restrict__ vTbuf) {
    __shared__ unsigned shbuf[128 * 68];  // 34KB: staging (32KB) / transpose T
    ushort_t* At = (ushort_t*)shbuf;
    ushort_t* Bt = At + 128 * 64;
    const int mb = blockIdx.x * 128;
    const int nb = blockIdx.y * 128;
    GEMM_KLOOP(A, BT)

    const int sec = nb >> 11;
    if (sec < 2) {
        // q/k: direct scatter (coalesced in d across lm)
#pragma unroll
        for (int mt = 0; mt < 4; ++mt)
#pragma unroll
            for (int nt = 0; nt < 4; ++nt)
#pragma unroll
                for (int r = 0; r < 4; ++r) {
                    int m = mb + wm + mt * 16 + lq * 4 + r;
                    int c = nb + wn + nt * 16 + lm;
                    float val = acc[mt][nt][r] + bias[c];
                    int h = (c >> 7) & 15;
                    int d = c & 127;
                    int b = m >> 11, s = m & 2047;
                    size_t bh = (size_t)(b * NH + h);
                    ushort_t* dst = (sec == 0) ? qbuf : kbuf;
                    dst[(bh * SEQ + s) * HD + d] = f2bf(val);
                }
    } else {
        // v: transpose in LDS, write vT[bh][d][s] coalesced
        __syncthreads();  // all waves done reading staging LDS
        unsigned* T = shbuf;  // [c(128)][68 uints], uint idx = c*68 + m/2
#pragma unroll
        for (int mt = 0; mt < 4; ++mt)
#pragma unroll
            for (int nt = 0; nt < 4; ++nt) {
                const int cl = wn + nt * 16 + lm;       // d 0..127
                const int ml = wm + mt * 16 + lq * 4;   // s-local base
                const float bb = bias[nb + cl];
#pragma unroll
                for (int r = 0; r < 4; r += 2) {
                    unsigned pk = (unsigned)f2bf(acc[mt][nt][r] + bb) |
                                  ((unsigned)f2bf(acc[mt][nt][r + 1] + bb) << 16);
                    T[cl * 68 + ((ml + r) >> 1)] = pk;
                }
            }
        __syncthreads();
        const int d = t & 127, sh = t >> 7;
        const int b = mb >> 11, sbase = mb & 2047;
        const int hv = (nb >> 7) - 32;
        ushort_t* vrow = vTbuf + ((size_t)(b * NH + hv) * HD + d) * SEQ + sbase + sh * 64;
#pragma unroll
        for (int i = 0; i < 8; ++i)
            *(uint4*)(vrow + i * 8) = *(const uint4*)&T[d * 68 + sh * 32 + i * 4];
    }
}

// GEMM 2: out = attn(bf16) @ w_proj + b_proj -> fp32
__global__ __launch_bounds__(256) void gemm_proj(
    const ushort_t* __restrict__ A, const ushort_t* __restrict__ BT,
    const float* __restrict__ bias, float* __restrict__ out) {
    __shared__ ushort_t Abuf[128 * 64];
    __shared__ ushort_t Bbuf[128 * 64];
    ushort_t* At = Abuf;
    ushort_t* Bt = Bbuf;
    const int mb = blockIdx.x * 128;
    const int nb = blockIdx.y * 128;
    GEMM_KLOOP(A, BT)
#pragma unroll
    for (int mt = 0; mt < 4; ++mt)
#pragma unroll
        for (int nt = 0; nt < 4; ++nt)
#pragma unroll
            for (int r = 0; r < 4; ++r) {
                int m = mb + wm + mt * 16 + lq * 4 + r;
                int c = nb + wn + nt * 16 + lm;
                out[(size_t)m * HID + c] = acc[mt][nt][r] + bias[c];
            }
}

// ---------------------------------------------------------------------------
// Flash attention, S^T = K Q^T. Grid 1024. XCD-pinned block mapping:
//   bid = g*8 + (bh&7), g = (31-qt)*4 + (bh>>3)
// -> all 32 q-tile blocks of one (b,h) share bid%8 (same XCD) so K/V stay in
// that XCD's L2 (was: 8x HBM re-fetch, 265MB). qt descending (LPT).
// Single-buffered K/V staging via global_load_lds(16B), XOR-swizzled chunks.
// ---------------------------------------------------------------------------
__global__ __launch_bounds__(256) void attn_kernel(
    const ushort_t* __restrict__ qb, const ushort_t* __restrict__ kbuf,
    const ushort_t* __restrict__ vT, ushort_t* __restrict__ ob) {
    __shared__ ushort_t Ks[64 * 128];   // [key][d] swizzled 16B chunks
    __shared__ ushort_t Vs[128 * 64];   // [d][key] swizzled 16B chunks
    __shared__ ushort_t Ps[4][16 * 72]; // per-wave P, row stride 72

    const int bid = blockIdx.x;
    const int x = bid & 7, g = bid >> 3;
    const int qt = 31 - (g >> 2);
    const int bh = ((g & 3) << 3) | x;
    const int qbase = qt * 64;
    const int t = threadIdx.x, w = t >> 6, lane = t & 63;
    const int lm = lane & 15, lq = lane >> 4;

    const ushort_t* Qg = qb + (size_t)bh * SEQ * HD;
    const ushort_t* Kg = kbuf + (size_t)bh * SEQ * HD;
    const ushort_t* Vg = vT + (size_t)bh * HD * SEQ;

    const float LOG2E = 1.44269504f;
    const int h = bh & 15;
    const float slope2 = exp2f(-0.5f * (float)(h + 1)) * LOG2E;
    const float scale2 = (1.0f / 128.0f) * LOG2E;

    const int qg = qbase + w * 16 + lm;  // this lane's q row

    // Q fragments direct from global (B-operand layout)
    bf16x8 qf[4];
#pragma unroll
    for (int kc = 0; kc < 4; ++kc) {
        uint4 qv = *(const uint4*)(Qg + (size_t)qg * HD + kc * 32 + lq * 8);
        qf[kc] = __builtin_bit_cast(bf16x8, qv);
    }

    float foff[4][4];
    int koff[4][4];
#pragma unroll
    for (int mt = 0; mt < 4; ++mt)
#pragma unroll
        for (int r = 0; r < 4; ++r) {
            koff[mt][r] = mt * 16 + lq * 4 + r;
            foff[mt][r] = slope2 * (float)koff[mt][r];
        }

    float mrow = -1e30f, lrow = 0.0f;
    f32x4 O[8] = {};
    const int nkt = qt + 1;

    for (int kt = 0; kt < nkt; ++kt) {
        __syncthreads();  // prev iteration's compute done
        // stage K [64][128] and V^T [128][64] via async DMA, swizzled
        {
            const ushort_t* Kt = Kg + (size_t)kt * 64 * HD;
#pragma unroll
            for (int i = 0; i < 4; ++i) {
                int ci = i * 256 + t;
                int kr = ci >> 4, ks = ci & 15;
                int kcg = (ks & 8) | ((ks & 7) ^ (kr & 7));
                gl2lds16(Kt + (size_t)kr * HD + kcg * 8, Ks + (i * 256 + w * 64) * 8);
                int vr = ci >> 3, vs = ci & 7;
                int vcg = vs ^ (vr & 7);
                gl2lds16(Vg + (size_t)vr * SEQ + kt * 64 + vcg * 8, Vs + (i * 256 + w * 64) * 8);
            }
        }
        __syncthreads();  // staging visible

        // S^T = K Q^T : per wave 64 keys x 16 q
        f32x4 sacc[4] = {};
#pragma unroll
        for (int kc = 0; kc < 4; ++kc) {
            const int slot = ((kc * 4 + lq) & 8) | (((kc * 4 + lq) & 7) ^ (lm & 7));
#pragma unroll
            for (int mt = 0; mt < 4; ++mt) {
                bf16x8 bk = *(const bf16x8*)&Ks[((mt * 16 + lm) * 16 + slot) * 8];
                sacc[mt] = __builtin_amdgcn_mfma_f32_16x16x32_bf16(bk, qf[kc], sacc[mt], 0, 0, 0);
            }
        }

        // scores (log2 domain); mask only on the diagonal tile
        const float sbase = slope2 * (float)(kt * 64 - qg);
        float sc[4][4];
        if (kt == qt) {
#pragma unroll
            for (int mt = 0; mt < 4; ++mt)
#pragma unroll
                for (int r = 0; r < 4; ++r) {
                    float s = sacc[mt][r] * scale2 + (sbase + foff[mt][r]);
                    sc[mt][r] = (kt * 64 + koff[mt][r] <= qg) ? s : -3e38f;
                }
        } else {
#pragma unroll
            for (int mt = 0; mt < 4; ++mt)
#pragma unroll
                for (int r = 0; r < 4; ++r)
                    sc[mt][r] = sacc[mt][r] * scale2 + (sbase + foff[mt][r]);
        }

        // row max: 15 in-lane + 2 shuffles
        float tm = sc[0][0];
#pragma unroll
        for (int mt = 0; mt < 4; ++mt)
#pragma unroll
            for (int r = 0; r < 4; ++r) tm = fmaxf(tm, sc[mt][r]);
        tm = fmaxf(tm, __shfl_xor(tm, 16));
        tm = fmaxf(tm, __shfl_xor(tm, 32));
        float mnew = fmaxf(mrow, tm);
        float alpha = __builtin_amdgcn_exp2f(mrow - mnew);
        mrow = mnew;

        // p = exp2(sc - m) -> Ps[q][key], sum
        float psum = 0.0f;
#pragma unroll
        for (int mt = 0; mt < 4; ++mt) {
            float p0 = __builtin_amdgcn_exp2f(sc[mt][0] - mnew);
            float p1 = __builtin_amdgcn_exp2f(sc[mt][1] - mnew);
            float p2 = __builtin_amdgcn_exp2f(sc[mt][2] - mnew);
            float p3 = __builtin_amdgcn_exp2f(sc[mt][3] - mnew);
            psum += (p0 + p1) + (p2 + p3);
            uint2 wv;
            wv.x = ((unsigned)f2bf(p1) << 16) | f2bf(p0);
            wv.y = ((unsigned)f2bf(p3) << 16) | f2bf(p2);
            *(uint2*)&Ps[w][lm * 72 + mt * 16 + lq * 4] = wv;
        }
        psum += __shfl_xor(psum, 16);
        psum += __shfl_xor(psum, 32);
        lrow = lrow * alpha + psum;

        // rescale O (O row q = lq*4+r; alpha lives at lane q = lm)
        float av[4];
#pragma unroll
        for (int r = 0; r < 4; ++r) av[r] = __shfl(alpha, lq * 4 + r);
#pragma unroll
        for (int nt = 0; nt < 8; ++nt)
#pragma unroll
            for (int r = 0; r < 4; ++r) O[nt][r] *= av[r];

        // PV: A = P (q=lane&15), B = V^T (swizzled)
        asm volatile("s_waitcnt lgkmcnt(0)" ::: "memory");
#pragma unroll
        for (int kc2 = 0; kc2 < 2; ++kc2) {
            bf16x8 ap = *(const bf16x8*)&Ps[w][lm * 72 + kc2 * 32 + lq * 8];
            const int slot = (kc2 * 4 + lq) ^ (lm & 7);
#pragma unroll
            for (int nt = 0; nt < 8; ++nt) {
                bf16x8 bv = *(const bf16x8*)&Vs[((nt * 16 + lm) * 8 + slot) * 8];
                O[nt] = __builtin_amdgcn_mfma_f32_16x16x32_bf16(ap, bv, O[nt], 0, 0, 0);
            }
        }
    }

    // epilogue
    float lb[4];
#pragma unroll
    for (int r = 0; r < 4; ++r)
        lb[r] = __builtin_amdgcn_rcpf(__shfl(lrow, lq * 4 + r));
    const int b = bh >> 4;
#pragma unroll
    for (int nt = 0; nt < 8; ++nt)
#pragma unroll
        for (int r = 0; r < 4; ++r) {
            int s = qbase + w * 16 + lq * 4 + r;
            int d = nt * 16 + lm;
            ob[((size_t)(b * SEQ + s)) * HID + h * HD + d] = f2bf(O[nt][r] * lb[r]);
        }
}

// ---------------------------------------------------------------------------
extern "C" void kernel_launch(void* const* d_in, const int* in_sizes, int n_in,
                              void* d_out, int out_size, void* d_ws, size_t ws_size,
                              hipStream_t stream) {
    const float* hidden = (const float*)d_in[0];
    const float* w_qkv = (const float*)d_in[1];
    const float* b_qkv = (const float*)d_in[2];
    const float* w_proj = (const float*)d_in[3];
    const float* b_proj = (const float*)d_in[4];
    float* out = (float*)d_out;

    char* ws = (char*)d_ws;
    size_t off = 0;
    ushort_t* wqkvT = (ushort_t*)(ws + off); off += (size_t)NQKV * HID * 2;
    ushort_t* wprojT = (ushort_t*)(ws + off); off += (size_t)HID * HID * 2;
    ushort_t* hbf = (ushort_t*)(ws + off); off += (size_t)BATCH * SEQ * HID * 2;
    ushort_t* qw = (ushort_t*)(ws + off); off += (size_t)BATCH * NH * SEQ * HD * 2;
    ushort_t* kw = (ushort_t*)(ws + off); off += (size_t)BATCH * NH * SEQ * HD * 2;
    ushort_t* vTw = (ushort_t*)(ws + off); off += (size_t)BATCH * NH * SEQ * HD * 2;
    ushort_t* attnw = (ushort_t*)(ws + off); off += (size_t)BATCH * SEQ * HID * 2;

    to_bf16<<<dim3(BATCH * SEQ * HID / 8 / 256), 256, 0, stream>>>(
        hidden, hbf, BATCH * SEQ * HID / 8);
    transpose_to_bf16<<<dim3(NQKV / 32, HID / 32), dim3(32, 8), 0, stream>>>(
        w_qkv, wqkvT, HID, NQKV);
    transpose_to_bf16<<<dim3(HID / 32, HID / 32), dim3(32, 8), 0, stream>>>(
        w_proj, wprojT, HID, HID);

    gemm_qkv<<<dim3(BATCH * SEQ / 128, NQKV / 128), 256, 0, stream>>>(
        hbf, wqkvT, b_qkv, qw, kw, vTw);

    attn_kernel<<<dim3(BATCH * NH * 32), 256, 0, stream>>>(qw, kw, vTw, attnw);

    gemm_proj<<<dim3(BATCH * SEQ / 128, HID / 128), 256, 0, stream>>>(
        attnw, wprojT, b_proj, out);
}